// Round 2
// 644.393 us; speedup vs baseline: 1.2125x; 1.2125x over previous
//
#include <hip/hip_runtime.h>

typedef unsigned short bf16_t;
typedef short s16x8 __attribute__((ext_vector_type(8)));
typedef float f32x4 __attribute__((ext_vector_type(4)));

// ===========================================================================
// Round 9 = Round 8 resubmit (R8 bench died with "container failed twice" --
// infra error, no kernel signal; code re-audited for fault vectors: none).
// R7 profile: k_gemm1 = 227us, MfmaUtil=0, VALUBusy=38%, HBM 4.3% -- a
// vector-ALU fp32 GEMM at 18% of the 157TF vector ceiling while the 2.5PF
// matrix pipe idles. FETCH=51.5MB proves x arrives as bf16 (100k*256*2B).
// Changes vs R7:
//  - k_gemm1/k_gemm2 -> MFMA (mfma_f32_16x16x32_bf16), no-LDS design:
//    per-lane 16B fragment loads straight from global (A rows / B^T rows),
//    no barriers in K-loop, latency hidden by occupancy.
//  - weights kept fp32-exact via hi/lo bf16 split (k_wsplit pre-transposes
//    W -> BT_hi[n][k], BT_lo[n][k]); two chained MFMAs per fragment.
//    MFMA is ~3us of work here -- doubling it is free; absmax unchanged.
//  - if x arrives fp32 (detector mode 1): split x hi/lo too (3 MFMAs) so
//    precision is never worse than R7's fp32 FMA path.
//  - gemm2 stays in-place over the ha panel; __syncthreads() between K-loop
//    and epilogue orders mu-writes after all A-reads (blocks row-disjoint,
//    tail clamp stays within the block's own rows).
// Fragment layouts (m89/m162-verified): A/B lane l: (m|n)=l&15, k=(l>>4)*8+j;
// C/D: col=l&15, row=(l>>4)*4+reg.
// ===========================================================================

__device__ __forceinline__ float bf2f(unsigned short u) {
    unsigned int v = ((unsigned int)u) << 16;
    float f;
    __builtin_memcpy(&f, &v, 4);
    return f;
}
__device__ __forceinline__ unsigned short f2bf(float f) {
    unsigned int x;
    __builtin_memcpy(&x, &f, 4);
    unsigned int r = x + 0x7fffu + ((x >> 16) & 1u);
    return (unsigned short)(r >> 16);
}
__device__ __forceinline__ unsigned pack2(float a, float b) {
    return (unsigned)f2bf(a) | ((unsigned)f2bf(b) << 16);
}
__device__ __forceinline__ float ldf(const void* p, long long i, unsigned f32) {
    return f32 ? ((const float*)p)[i] : bf2f(((const unsigned short*)p)[i]);
}
__device__ __forceinline__ int ldi(const void* p, long long i, unsigned i64) {
    return i64 ? (int)((const long long*)p)[i] : ((const int*)p)[i];
}
__device__ __forceinline__ s16x8 ld8u(const unsigned short* p) {
    return *(const s16x8*)p;   // 16B aligned at all call sites
}
__device__ __forceinline__ f32x4 mfma16(s16x8 a, s16x8 b, f32x4 c) {
    return __builtin_amdgcn_mfma_f32_16x16x32_bf16(a, b, c, 0, 0, 0);
}
// fp32 -> (hi, lo) bf16 fragments, 8 consecutive floats
__device__ __forceinline__ void cvt_hl(const float* p, s16x8& hi, s16x8& lo) {
    const float4 u = *(const float4*)p;
    const float4 w = *(const float4*)(p + 4);
    float v[8] = {u.x, u.y, u.z, u.w, w.x, w.y, w.z, w.w};
#pragma unroll
    for (int j = 0; j < 8; ++j) {
        unsigned short h = f2bf(v[j]);
        hi[j] = (short)h;
        lo[j] = (short)f2bf(v[j] - bf2f(h));
    }
}

__global__ __launch_bounds__(256) void k_zero(unsigned* __restrict__ p, int n) {
    int i = blockIdx.x * 256 + threadIdx.x;
    if (i < n) p[i] = 0;
}

// ---- format detector: flags[0]=x_f32, flags[1]=W_f32, flags[2]=ei_i64 ------
__global__ __launch_bounds__(256) void k_detect(const void* x, const void* W1,
                                                const void* ei, unsigned* flags) {
    __shared__ float smx[256];
    __shared__ float smw[256];
    __shared__ int   szc[256];
    int tid = threadIdx.x;
    const unsigned short* xu = (const unsigned short*)x;
    float mx = 0.f;
    for (int i = tid; i < 4096; i += 256) {
        unsigned short w = xu[i];
        if ((w & 0x7fffu) >= 0x7f80u) mx = 1e30f;
        else { float f = fabsf(bf2f(w)); if (f > mx) mx = f; }
    }
    smx[tid] = mx;
    const unsigned short* wu = (const unsigned short*)W1;
    float mw = 0.f;
    for (int i = tid; i < 4096; i += 256) {
        unsigned short w = wu[i];
        if ((w & 0x7fffu) >= 0x7f80u) mw = 1e30f;
        else { float f = fabsf(bf2f(w)); if (f > mw) mw = f; }
    }
    smw[tid] = mw;
    const int* eu = (const int*)ei;
    int zc = 0;
    for (int i = tid; i < 128; i += 256)
        if ((i & 1) && eu[i] == 0) ++zc;
    szc[tid] = zc;
    __syncthreads();
    for (int off = 128; off > 0; off >>= 1) {
        if (tid < off) {
            if (smx[tid + off] > smx[tid]) smx[tid] = smx[tid + off];
            if (smw[tid + off] > smw[tid]) smw[tid] = smw[tid + off];
            szc[tid] += szc[tid + off];
        }
        __syncthreads();
    }
    if (tid == 0) {
        flags[0] = (smx[0] > 1e4f) ? 1u : 0u;
        flags[1] = (smw[0] > 10.f) ? 1u : 0u;
        flags[2] = (szc[0] >= 56) ? 1u : 0u;
    }
}

// ---- degree count ----------------------------------------------------------
__global__ __launch_bounds__(256) void k_count(const void* ei, const unsigned* det,
                                               int* __restrict__ cnt, int E, int N) {
    int e = blockIdx.x * 256 + threadIdx.x;
    if (e >= E) return;
    int d = ldi(ei, (long long)E + e, det[2]);
    if ((unsigned)d < (unsigned)N) atomicAdd(&cnt[d], 1);
}

__global__ __launch_bounds__(256) void k_dinv(const int* __restrict__ cnt,
                                              float* __restrict__ dinv, int N) {
    int i = blockIdx.x * 256 + threadIdx.x;
    if (i < N) dinv[i] = rsqrtf((float)cnt[i] + 1.0f);  // +1 self-loop
}

// ---- exclusive scan (3-phase) ----------------------------------------------
__global__ __launch_bounds__(256) void k_scan_blk(const int* __restrict__ cnt,
                                                  int* __restrict__ pos,
                                                  int* __restrict__ bsum, int N) {
    __shared__ int sh[256];
    const int tid = threadIdx.x;
    const int base = blockIdx.x * 1024 + tid * 4;
    int v[4];
#pragma unroll
    for (int j = 0; j < 4; ++j) v[j] = (base + j < N) ? cnt[base + j] : 0;
    int s = v[0] + v[1] + v[2] + v[3];
    sh[tid] = s;
    __syncthreads();
    for (int off = 1; off < 256; off <<= 1) {
        int t = (tid >= off) ? sh[tid - off] : 0;
        __syncthreads();
        sh[tid] += t;
        __syncthreads();
    }
    int run = sh[tid] - s;
#pragma unroll
    for (int j = 0; j < 4; ++j) {
        if (base + j < N) pos[base + j] = run;
        run += v[j];
    }
    if (tid == 255) bsum[blockIdx.x] = sh[255];
}

__global__ void k_scan_top(int* __restrict__ bsum, int nb) {
    if (threadIdx.x == 0 && blockIdx.x == 0) {
        int running = 0;
        for (int b = 0; b < nb; ++b) {
            int t = bsum[b];
            bsum[b] = running;
            running += t;
        }
    }
}

__global__ __launch_bounds__(256) void k_scan_add(int* __restrict__ pos,
                                                  const int* __restrict__ bsum, int N) {
    int add = bsum[blockIdx.x];
    int base = blockIdx.x * 1024;
    for (int i = threadIdx.x; i < 1024; i += 256)
        if (base + i < N) pos[base + i] += add;
}

// ---- CSR fill --------------------------------------------------------------
__global__ __launch_bounds__(256) void k_fill(const void* ei, const unsigned* det,
                                              int* __restrict__ pos,
                                              int* __restrict__ srt, int E, int N) {
    int e = blockIdx.x * 256 + threadIdx.x;
    if (e >= E) return;
    unsigned i64 = det[2];
    int s = ldi(ei, e, i64);
    int d = ldi(ei, (long long)E + e, i64);
    if ((unsigned)d < (unsigned)N) {
        int slot = atomicAdd(&pos[d], 1);
        srt[slot] = ((unsigned)s < (unsigned)N) ? s : d;
    }
}

// ---- weight transpose + hi/lo bf16 split -----------------------------------
// out BT_hi/BT_lo [128 n][K k] bf16; w ~= hi + lo to ~2^-17 relative.
// Wb==null: Wa is [K][128]. Wb!=null: cols 0..63 from Wa[K][64], 64..127 Wb.
__global__ __launch_bounds__(256) void k_wsplit(const void* Wa, const void* Wb,
                                                const unsigned* det, int K,
                                                unsigned short* __restrict__ bth,
                                                unsigned short* __restrict__ btl) {
    int idx = blockIdx.x * 256 + threadIdx.x;
    if (idx >= K * 128) return;
    int k = idx >> 7, n = idx & 127;
    unsigned wf = det[1];
    float w;
    if (Wb) w = (n < 64) ? ldf(Wa, (long long)k * 64 + n, wf)
                         : ldf(Wb, (long long)k * 64 + (n - 64), wf);
    else    w = ldf(Wa, idx, wf);
    unsigned short h = f2bf(w);
    bth[(long long)n * K + k] = h;
    btl[(long long)n * K + k] = f2bf(w - bf2f(h));
}

// ---- gemm1 (MFMA): h0'[N,128](bf16) = (x[N,256] @ W1) * dinv[row] ----------
// 64 rows x 128 cols per block; 4 waves in 2x2; wave tile 32x64 = 2x4 frags.
// No LDS: per-lane 16B fragment loads from global (x rows / BT rows).
__global__ __launch_bounds__(256, 4) void k_gemm1m(
    const void* __restrict__ x, const unsigned* __restrict__ det,
    const unsigned short* __restrict__ bth,
    const unsigned short* __restrict__ btl,
    const float* __restrict__ dinv,
    unsigned* __restrict__ Cp, int N) {
    const int lane = threadIdx.x & 63;
    const int wid  = threadIdx.x >> 6;
    const int wr = wid >> 1, wc = wid & 1;
    const int l15 = lane & 15, lg = lane >> 4;
    const long long r0 = (long long)blockIdx.x * 64 + wr * 32;
    long long ar[2];
#pragma unroll
    for (int m = 0; m < 2; ++m) {
        long long r = r0 + m * 16 + l15;
        ar[m] = (r < N) ? r : (N - 1);           // clamp: tail block reads valid rows
    }
    int bn[4];
#pragma unroll
    for (int n = 0; n < 4; ++n) bn[n] = wc * 64 + n * 16 + l15;

    f32x4 acc[2][4] = {};
    if (!det[0]) {                                // x is bf16
        const unsigned short* xp = (const unsigned short*)x;
#pragma unroll 2
        for (int k0 = 0; k0 < 256; k0 += 32) {
            const int kb = k0 + lg * 8;
            s16x8 a[2], bh[4], bl[4];
#pragma unroll
            for (int m = 0; m < 2; ++m) a[m] = ld8u(xp + ar[m] * 256 + kb);
#pragma unroll
            for (int n = 0; n < 4; ++n) {
                bh[n] = ld8u(bth + (long long)bn[n] * 256 + kb);
                bl[n] = ld8u(btl + (long long)bn[n] * 256 + kb);
            }
#pragma unroll
            for (int m = 0; m < 2; ++m)
#pragma unroll
                for (int n = 0; n < 4; ++n) {
                    acc[m][n] = mfma16(a[m], bh[n], acc[m][n]);
                    acc[m][n] = mfma16(a[m], bl[n], acc[m][n]);
                }
        }
    } else {                                      // x is fp32: split hi/lo too
        const float* xp = (const float*)x;
#pragma unroll 2
        for (int k0 = 0; k0 < 256; k0 += 32) {
            const int kb = k0 + lg * 8;
            s16x8 ah[2], al[2], bh[4], bl[4];
#pragma unroll
            for (int m = 0; m < 2; ++m) cvt_hl(xp + ar[m] * 256 + kb, ah[m], al[m]);
#pragma unroll
            for (int n = 0; n < 4; ++n) {
                bh[n] = ld8u(bth + (long long)bn[n] * 256 + kb);
                bl[n] = ld8u(btl + (long long)bn[n] * 256 + kb);
            }
#pragma unroll
            for (int m = 0; m < 2; ++m)
#pragma unroll
                for (int n = 0; n < 4; ++n) {
                    acc[m][n] = mfma16(ah[m], bh[n], acc[m][n]);
                    acc[m][n] = mfma16(ah[m], bl[n], acc[m][n]);
                    acc[m][n] = mfma16(al[m], bh[n], acc[m][n]);
                }
        }
    }
    // epilogue: scale by dinv[row], pair even/odd cols via shfl, pack bf16
#pragma unroll
    for (int m = 0; m < 2; ++m)
#pragma unroll
        for (int n = 0; n < 4; ++n) {
            const int col = wc * 64 + n * 16 + l15;
#pragma unroll
            for (int r = 0; r < 4; ++r) {
                long long row = r0 + m * 16 + lg * 4 + r;
                float v = acc[m][n][r] * dinv[(row < N) ? row : (N - 1)];
                float p = __shfl_xor(v, 1);
                if (!(lane & 1) && row < N)
                    Cp[row * 64 + (col >> 1)] = pack2(v, p);
            }
        }
}

// ---- gemm2 (MFMA): [mu|lv](fp32) = ha[N,128](bf16) @ [Wmu;Wlv] + bias ------
// In-place over the ha panel (Mp): wc=0 waves write mu into the dwords that
// wc=1 waves read as A -> __syncthreads() between K-loop and epilogue.
__global__ __launch_bounds__(256, 4) void k_gemm2m(
    const unsigned short* __restrict__ hap,
    const unsigned short* __restrict__ bth,
    const unsigned short* __restrict__ btl,
    const void* bmu, const void* blv, const unsigned* __restrict__ det,
    float* __restrict__ outMu, float* __restrict__ outLv, int N) {
    const int lane = threadIdx.x & 63;
    const int wid  = threadIdx.x >> 6;
    const int wr = wid >> 1, wc = wid & 1;
    const int l15 = lane & 15, lg = lane >> 4;
    const long long r0 = (long long)blockIdx.x * 64 + wr * 32;
    long long ar[2];
#pragma unroll
    for (int m = 0; m < 2; ++m) {
        long long r = r0 + m * 16 + l15;
        ar[m] = (r < N) ? r : (N - 1);
    }
    int bn[4];
#pragma unroll
    for (int n = 0; n < 4; ++n) bn[n] = wc * 64 + n * 16 + l15;

    f32x4 acc[2][4] = {};
#pragma unroll
    for (int k0 = 0; k0 < 128; k0 += 32) {
        const int kb = k0 + lg * 8;
        s16x8 a[2], bh[4], bl[4];
#pragma unroll
        for (int m = 0; m < 2; ++m) a[m] = ld8u(hap + ar[m] * 128 + kb);
#pragma unroll
        for (int n = 0; n < 4; ++n) {
            bh[n] = ld8u(bth + (long long)bn[n] * 128 + kb);
            bl[n] = ld8u(btl + (long long)bn[n] * 128 + kb);
        }
#pragma unroll
        for (int m = 0; m < 2; ++m)
#pragma unroll
            for (int n = 0; n < 4; ++n) {
                acc[m][n] = mfma16(a[m], bh[n], acc[m][n]);
                acc[m][n] = mfma16(a[m], bl[n], acc[m][n]);
            }
    }
    __syncthreads();   // all A-reads done before any in-place mu write
    const unsigned wf = det[1];
#pragma unroll
    for (int m = 0; m < 2; ++m)
#pragma unroll
        for (int n = 0; n < 4; ++n) {
            const int col = wc * 64 + n * 16 + l15;
            const float bias = (col < 64) ? ldf(bmu, col, wf)
                                          : ldf(blv, col - 64, wf);
#pragma unroll
            for (int r = 0; r < 4; ++r) {
                long long row = r0 + m * 16 + lg * 4 + r;
                if (row < N) {
                    float v = acc[m][n][r] + bias;
                    if (col < 64) outMu[row * 64 + col] = v;
                    else          outLv[row * 64 + (col - 64)] = v;
                }
            }
        }
}

// ---- gather over pre-scaled bf16[N,128] panel ------------------------------
// out[node] = op( dinv[node] * (sum_{s in nbrs} h'[s] + h'[node]) )
// one wave/node, 2 cols/lane (1 dword), 8-way predicated unroll.
__global__ __launch_bounds__(256) void k_gather(const unsigned* __restrict__ hp,
                                                const int* __restrict__ srt,
                                                const int* __restrict__ cnt,
                                                const int* __restrict__ pos,
                                                const float* __restrict__ dinv,
                                                const void* bias, const unsigned* det,
                                                int leaky, int prescaleOut,
                                                unsigned* __restrict__ outp, int N) {
    int node = blockIdx.x * 4 + (threadIdx.x >> 6);
    if (node >= N) return;
    int lane = threadIdx.x & 63;
    int end = pos[node];
    int beg = end - cnt[node];
    float dd = dinv[node];
    unsigned hv = hp[(long long)node * 64 + lane];
    float a0 = bf2f((unsigned short)(hv & 0xffffu));
    float a1 = bf2f((unsigned short)(hv >> 16));
    for (int q = beg; q < end; q += 8) {
        int s[8];
        unsigned v[8];
#pragma unroll
        for (int j = 0; j < 8; ++j) {
            int qq = q + j;
            s[j] = srt[(qq < end) ? qq : beg];   // loop entered => beg valid
        }
#pragma unroll
        for (int j = 0; j < 8; ++j)
            v[j] = hp[(long long)s[j] * 64 + lane];
#pragma unroll
        for (int j = 0; j < 8; ++j) {
            bool on = (q + j) < end;
            a0 += on ? bf2f((unsigned short)(v[j] & 0xffffu)) : 0.f;
            a1 += on ? bf2f((unsigned short)(v[j] >> 16)) : 0.f;
        }
    }
    a0 *= dd;
    a1 *= dd;
    if (bias) {
        a0 += ldf(bias, 2 * lane, det[1]);
        a1 += ldf(bias, 2 * lane + 1, det[1]);
    }
    if (leaky) {
        a0 = (a0 >= 0.f) ? a0 : 0.01f * a0;
        a1 = (a1 >= 0.f) ? a1 : 0.01f * a1;
    }
    if (prescaleOut) { a0 *= dd; a1 *= dd; }
    outp[(long long)node * 64 + lane] = pack2(a0, a1);
}

__global__ void k_sentinel(float* out, long long lvOff) {
    if (threadIdx.x == 0 && blockIdx.x == 0) {
        out[0] = 9.99e5f;
        out[lvOff] = 9.98e5f;
    }
}

extern "C" void kernel_launch(void* const* d_in, const int* in_sizes, int n_in,
                              void* d_out, int out_size, void* d_ws, size_t ws_size,
                              hipStream_t stream) {
    (void)out_size;
    const int N = 100000, E = 1600000;
    bool ok = (n_in == 8) && in_sizes[0] == 25600000 && in_sizes[1] == 3200000 &&
              in_sizes[2] == 32768 && in_sizes[3] == 128 &&
              in_sizes[4] == 8192 && in_sizes[5] == 64 &&
              in_sizes[6] == 8192 && in_sizes[7] == 64 &&
              ws_size >= (size_t)10 * 1024 * 1024;
    if (!ok) {
        k_sentinel<<<1, 64, 0, stream>>>((float*)d_out, (long long)N * 64);
        return;
    }
    const void* x   = d_in[0];
    const void* ei  = d_in[1];
    const void* W1  = d_in[2];
    const void* b1  = d_in[3];
    const void* Wmu = d_in[4];
    const void* bmu = d_in[5];
    const void* Wlv = d_in[6];
    const void* blv = d_in[7];

    char* w = (char*)d_ws;
    auto carve = [&](size_t bytes) {
        char* p = w;
        w += (bytes + 255) & ~(size_t)255;
        return p;
    };
    unsigned* flags = (unsigned*)carve(64);
    int*    cnt  = (int*)carve((size_t)N * 4);
    int*    pos  = (int*)carve((size_t)N * 4);
    float*  dinv = (float*)carve((size_t)N * 4);
    int*    bsum = (int*)carve(4096);
    int*    srt  = (int*)carve((size_t)E * 4);
    unsigned short* bt1h = (unsigned short*)carve(128 * 256 * 2);  // 64KB
    unsigned short* bt1l = (unsigned short*)carve(128 * 256 * 2);
    unsigned short* bt2h = (unsigned short*)carve(128 * 128 * 2);  // 32KB
    unsigned short* bt2l = (unsigned short*)carve(128 * 128 * 2);  // ~7.9MB total

    float* M = (float*)d_out;                  // mu region / panel storage
    float* L = M + (size_t)N * 64;             // logvar region / panel storage
    unsigned* Mp = (unsigned*)M;               // bf16[N,128] as dword[N*64]
    unsigned* Lp = (unsigned*)L;

    const int nb = (N + 1023) / 1024;
    const int gblk = (N + 3) / 4;
    const int gb64 = (N + 63) / 64;            // 1563 (tail block: 32 rows)

    k_zero<<<1, 64, 0, stream>>>(flags, 16);
    k_detect<<<1, 256, 0, stream>>>(x, W1, ei, flags);
    k_zero<<<(N + 255) / 256, 256, 0, stream>>>((unsigned*)cnt, N);

    k_count<<<(E + 255) / 256, 256, 0, stream>>>(ei, flags, cnt, E, N);
    k_dinv<<<(N + 255) / 256, 256, 0, stream>>>(cnt, dinv, N);
    k_scan_blk<<<nb, 256, 0, stream>>>(cnt, pos, bsum, N);
    k_scan_top<<<1, 64, 0, stream>>>(bsum, nb);
    k_scan_add<<<nb, 256, 0, stream>>>(pos, bsum, N);
    k_fill<<<(E + 255) / 256, 256, 0, stream>>>(ei, flags, pos, srt, E, N);

    // weight transpose + hi/lo split (tiny; L2-resident thereafter)
    k_wsplit<<<(256 * 128 + 255) / 256, 256, 0, stream>>>(W1, nullptr, flags, 256,
                                                          bt1h, bt1l);
    k_wsplit<<<(128 * 128 + 255) / 256, 256, 0, stream>>>(Wmu, Wlv, flags, 128,
                                                          bt2h, bt2l);

    // h0' = (x@W1) * dinv[row]  -> bf16 panel in M   (MFMA)
    k_gemm1m<<<gb64, 256, 0, stream>>>(x, flags, bt1h, bt1l, dinv, Mp, N);
    // h'  = leaky(dd*(sum+self) + b1) * dd -> bf16 panel in L
    k_gather<<<gblk, 256, 0, stream>>>(Mp, srt, cnt, pos, dinv, b1, flags, 1, 1,
                                       Lp, N);
    // ha  = dd*(sum+self) -> bf16 panel in M (h0' dead)
    k_gather<<<gblk, 256, 0, stream>>>(Lp, srt, cnt, pos, dinv, nullptr, flags,
                                       0, 0, Mp, N);
    // [mu|lv] = ha @ [Wmu;Wlv] + bias -> fp32 M/L in-place   (MFMA)
    k_gemm2m<<<gb64, 256, 0, stream>>>((const unsigned short*)Mp, bt2h, bt2l,
                                       bmu, blv, flags, M, L, N);
}

// Round 3
// 560.392 us; speedup vs baseline: 1.3943x; 1.1499x over previous
//
#include <hip/hip_runtime.h>

typedef unsigned short bf16_t;
typedef short s16x8 __attribute__((ext_vector_type(8)));
typedef float f32x4 __attribute__((ext_vector_type(4)));

// ===========================================================================
// Round 10 (R9 passed @644us). R9 profile: k_fill = 132us top dispatch,
// WRITE_SIZE=105.8MB for a 6.4MB logical output -> 16.5x (64B/edge) write
// amplification from random 4B CSR scatter across non-coherent XCD L2s;
// VALUBusy=0.4% (pure memory/atomic). k_count has the same atomic pattern.
// Changes:
//  - k_count + k_fill replaced by bucketed counting sort:
//    k_bucket: append packed 4B recs ((dst&127)<<24|src) into 782 buckets
//      (dst>>7) x 8 XCD-local substreams (blockIdx&7 ~ XCD, m157); counters
//      sub-major so counter lines never cross XCDs; writes = append streams.
//    k_bhist: per-bucket LDS histogram -> cnt (coalesced; replaces 1.6M
//      device atomics with LDS atomics).
//    k_emit (post-scan): LDS placement + fully-coalesced srt write.
//    cap 512/cell = mean 256 + 16sigma for uniform-random edges.
//  - pos no longer mutated: k_gather uses beg=pos, end=beg+cnt.
//  - ws usage ~20.6MB; guard raised to 21MiB (session-measured ws>=23MiB).
// MFMA gemms (R9) unchanged: hi/lo-split bf16 weights, no-LDS fragment loads.
// ===========================================================================

#define NBKT 782   // ceil(100000/128) buckets of 128 nodes
#define BSH  7
#define BMSK 127
#define CAPS 512   // per (bucket,sub) capacity: mean 256 + 16 sigma

__device__ __forceinline__ float bf2f(unsigned short u) {
    unsigned int v = ((unsigned int)u) << 16;
    float f;
    __builtin_memcpy(&f, &v, 4);
    return f;
}
__device__ __forceinline__ unsigned short f2bf(float f) {
    unsigned int x;
    __builtin_memcpy(&x, &f, 4);
    unsigned int r = x + 0x7fffu + ((x >> 16) & 1u);
    return (unsigned short)(r >> 16);
}
__device__ __forceinline__ unsigned pack2(float a, float b) {
    return (unsigned)f2bf(a) | ((unsigned)f2bf(b) << 16);
}
__device__ __forceinline__ float ldf(const void* p, long long i, unsigned f32) {
    return f32 ? ((const float*)p)[i] : bf2f(((const unsigned short*)p)[i]);
}
__device__ __forceinline__ int ldi(const void* p, long long i, unsigned i64) {
    return i64 ? (int)((const long long*)p)[i] : ((const int*)p)[i];
}
__device__ __forceinline__ s16x8 ld8u(const unsigned short* p) {
    return *(const s16x8*)p;   // 16B aligned at all call sites
}
__device__ __forceinline__ f32x4 mfma16(s16x8 a, s16x8 b, f32x4 c) {
    return __builtin_amdgcn_mfma_f32_16x16x32_bf16(a, b, c, 0, 0, 0);
}
// fp32 -> (hi, lo) bf16 fragments, 8 consecutive floats
__device__ __forceinline__ void cvt_hl(const float* p, s16x8& hi, s16x8& lo) {
    const float4 u = *(const float4*)p;
    const float4 w = *(const float4*)(p + 4);
    float v[8] = {u.x, u.y, u.z, u.w, w.x, w.y, w.z, w.w};
#pragma unroll
    for (int j = 0; j < 8; ++j) {
        unsigned short h = f2bf(v[j]);
        hi[j] = (short)h;
        lo[j] = (short)f2bf(v[j] - bf2f(h));
    }
}

__global__ __launch_bounds__(256) void k_zero(unsigned* __restrict__ p, int n) {
    int i = blockIdx.x * 256 + threadIdx.x;
    if (i < n) p[i] = 0;
}

// ---- format detector: flags[0]=x_f32, flags[1]=W_f32, flags[2]=ei_i64 ------
__global__ __launch_bounds__(256) void k_detect(const void* x, const void* W1,
                                                const void* ei, unsigned* flags) {
    __shared__ float smx[256];
    __shared__ float smw[256];
    __shared__ int   szc[256];
    int tid = threadIdx.x;
    const unsigned short* xu = (const unsigned short*)x;
    float mx = 0.f;
    for (int i = tid; i < 4096; i += 256) {
        unsigned short w = xu[i];
        if ((w & 0x7fffu) >= 0x7f80u) mx = 1e30f;
        else { float f = fabsf(bf2f(w)); if (f > mx) mx = f; }
    }
    smx[tid] = mx;
    const unsigned short* wu = (const unsigned short*)W1;
    float mw = 0.f;
    for (int i = tid; i < 4096; i += 256) {
        unsigned short w = wu[i];
        if ((w & 0x7fffu) >= 0x7f80u) mw = 1e30f;
        else { float f = fabsf(bf2f(w)); if (f > mw) mw = f; }
    }
    smw[tid] = mw;
    const int* eu = (const int*)ei;
    int zc = 0;
    for (int i = tid; i < 128; i += 256)
        if ((i & 1) && eu[i] == 0) ++zc;
    szc[tid] = zc;
    __syncthreads();
    for (int off = 128; off > 0; off >>= 1) {
        if (tid < off) {
            if (smx[tid + off] > smx[tid]) smx[tid] = smx[tid + off];
            if (smw[tid + off] > smw[tid]) smw[tid] = smw[tid + off];
            szc[tid] += szc[tid + off];
        }
        __syncthreads();
    }
    if (tid == 0) {
        flags[0] = (smx[0] > 1e4f) ? 1u : 0u;
        flags[1] = (smw[0] > 10.f) ? 1u : 0u;
        flags[2] = (szc[0] >= 56) ? 1u : 0u;
    }
}

// ---- phase A: bucket scatter (append streams, XCD-local counters) ----------
__global__ __launch_bounds__(256) void k_bucket(const void* ei, const unsigned* det,
                                                int* __restrict__ btail,
                                                unsigned* __restrict__ bstore,
                                                int E, int N) {
    int e = blockIdx.x * 256 + threadIdx.x;
    if (e >= E) return;
    unsigned i64 = det[2];
    int s = ldi(ei, e, i64);
    int d = ldi(ei, (long long)E + e, i64);
    if ((unsigned)d >= (unsigned)N) return;
    int b = d >> BSH;
    int sub = blockIdx.x & 7;
    int slot = atomicAdd(&btail[sub * NBKT + b], 1);
    if (slot < CAPS) {
        unsigned src = ((unsigned)s < (unsigned)N) ? (unsigned)s : (unsigned)d;
        bstore[((long long)(b * 8 + sub)) * CAPS + slot] =
            ((unsigned)(d & BMSK) << 24) | src;
    }
}

// ---- phase B1: per-bucket histogram -> cnt (coalesced write) ---------------
__global__ __launch_bounds__(256) void k_bhist(const int* __restrict__ btail,
                                               const unsigned* __restrict__ bstore,
                                               int* __restrict__ cnt, int N) {
    __shared__ int lh[128];
    __shared__ int ln[8];
    const int b = blockIdx.x;
    const int tid = threadIdx.x;
    if (tid < 128) lh[tid] = 0;
    if (tid < 8) {
        int t = btail[tid * NBKT + b];
        ln[tid] = t < CAPS ? t : CAPS;
    }
    __syncthreads();
#pragma unroll 1
    for (int s = 0; s < 8; ++s) {
        int n = ln[s];
        const unsigned* base = &bstore[((long long)(b * 8 + s)) * CAPS];
        for (int i = tid; i < n; i += 256)
            atomicAdd(&lh[base[i] >> 24], 1);
    }
    __syncthreads();
    int node = b * 128 + tid;
    if (tid < 128 && node < N) cnt[node] = lh[tid];
}

__global__ __launch_bounds__(256) void k_dinv(const int* __restrict__ cnt,
                                              float* __restrict__ dinv, int N) {
    int i = blockIdx.x * 256 + threadIdx.x;
    if (i < N) dinv[i] = rsqrtf((float)cnt[i] + 1.0f);  // +1 self-loop
}

// ---- exclusive scan (3-phase) ----------------------------------------------
__global__ __launch_bounds__(256) void k_scan_blk(const int* __restrict__ cnt,
                                                  int* __restrict__ pos,
                                                  int* __restrict__ bsum, int N) {
    __shared__ int sh[256];
    const int tid = threadIdx.x;
    const int base = blockIdx.x * 1024 + tid * 4;
    int v[4];
#pragma unroll
    for (int j = 0; j < 4; ++j) v[j] = (base + j < N) ? cnt[base + j] : 0;
    int s = v[0] + v[1] + v[2] + v[3];
    sh[tid] = s;
    __syncthreads();
    for (int off = 1; off < 256; off <<= 1) {
        int t = (tid >= off) ? sh[tid - off] : 0;
        __syncthreads();
        sh[tid] += t;
        __syncthreads();
    }
    int run = sh[tid] - s;
#pragma unroll
    for (int j = 0; j < 4; ++j) {
        if (base + j < N) pos[base + j] = run;
        run += v[j];
    }
    if (tid == 255) bsum[blockIdx.x] = sh[255];
}

__global__ void k_scan_top(int* __restrict__ bsum, int nb) {
    if (threadIdx.x == 0 && blockIdx.x == 0) {
        int running = 0;
        for (int b = 0; b < nb; ++b) {
            int t = bsum[b];
            bsum[b] = running;
            running += t;
        }
    }
}

__global__ __launch_bounds__(256) void k_scan_add(int* __restrict__ pos,
                                                  const int* __restrict__ bsum, int N) {
    int add = bsum[blockIdx.x];
    int base = blockIdx.x * 1024;
    for (int i = threadIdx.x; i < 1024; i += 256)
        if (base + i < N) pos[base + i] += add;
}

// ---- phase B2: per-bucket placement + coalesced srt write ------------------
__global__ __launch_bounds__(256) void k_emit(const int* __restrict__ btail,
                                              const unsigned* __restrict__ bstore,
                                              const int* __restrict__ pos,
                                              int* __restrict__ srt, int N) {
    __shared__ int lstart[128];
    __shared__ int loff[128];
    __shared__ int ln[8];
    __shared__ int stage[4096];   // <= 8*CAPS
    const int b = blockIdx.x;
    const int tid = threadIdx.x;
    const int base0 = pos[b * 128];          // b*128 <= 99968 < N always
    if (tid < 128) {
        int node = b * 128 + tid;
        lstart[tid] = (node < N) ? (pos[node] - base0) : 0;
        loff[tid] = 0;
    }
    if (tid < 8) {
        int t = btail[tid * NBKT + b];
        ln[tid] = t < CAPS ? t : CAPS;
    }
    __syncthreads();
#pragma unroll 1
    for (int s = 0; s < 8; ++s) {
        int n = ln[s];
        const unsigned* bp = &bstore[((long long)(b * 8 + s)) * CAPS];
        for (int i = tid; i < n; i += 256) {
            unsigned rec = bp[i];
            int dl = rec >> 24;
            int slot = atomicAdd(&loff[dl], 1);
            stage[lstart[dl] + slot] = (int)(rec & 0xffffffu);
        }
    }
    __syncthreads();
    int total = ln[0] + ln[1] + ln[2] + ln[3] + ln[4] + ln[5] + ln[6] + ln[7];
    for (int i = tid; i < total; i += 256)
        srt[base0 + i] = stage[i];
}

// ---- weight transpose + hi/lo bf16 split -----------------------------------
// out BT_hi/BT_lo [128 n][K k] bf16; w ~= hi + lo to ~2^-17 relative.
// Wb==null: Wa is [K][128]. Wb!=null: cols 0..63 from Wa[K][64], 64..127 Wb.
__global__ __launch_bounds__(256) void k_wsplit(const void* Wa, const void* Wb,
                                                const unsigned* det, int K,
                                                unsigned short* __restrict__ bth,
                                                unsigned short* __restrict__ btl) {
    int idx = blockIdx.x * 256 + threadIdx.x;
    if (idx >= K * 128) return;
    int k = idx >> 7, n = idx & 127;
    unsigned wf = det[1];
    float w;
    if (Wb) w = (n < 64) ? ldf(Wa, (long long)k * 64 + n, wf)
                         : ldf(Wb, (long long)k * 64 + (n - 64), wf);
    else    w = ldf(Wa, idx, wf);
    unsigned short h = f2bf(w);
    bth[(long long)n * K + k] = h;
    btl[(long long)n * K + k] = f2bf(w - bf2f(h));
}

// ---- gemm1 (MFMA): h0'[N,128](bf16) = (x[N,256] @ W1) * dinv[row] ----------
// 64 rows x 128 cols per block; 4 waves in 2x2; wave tile 32x64 = 2x4 frags.
// No LDS: per-lane 16B fragment loads from global (x rows / BT rows).
__global__ __launch_bounds__(256, 4) void k_gemm1m(
    const void* __restrict__ x, const unsigned* __restrict__ det,
    const unsigned short* __restrict__ bth,
    const unsigned short* __restrict__ btl,
    const float* __restrict__ dinv,
    unsigned* __restrict__ Cp, int N) {
    const int lane = threadIdx.x & 63;
    const int wid  = threadIdx.x >> 6;
    const int wr = wid >> 1, wc = wid & 1;
    const int l15 = lane & 15, lg = lane >> 4;
    const long long r0 = (long long)blockIdx.x * 64 + wr * 32;
    long long ar[2];
#pragma unroll
    for (int m = 0; m < 2; ++m) {
        long long r = r0 + m * 16 + l15;
        ar[m] = (r < N) ? r : (N - 1);           // clamp: tail block reads valid rows
    }
    int bn[4];
#pragma unroll
    for (int n = 0; n < 4; ++n) bn[n] = wc * 64 + n * 16 + l15;

    f32x4 acc[2][4] = {};
    if (!det[0]) {                                // x is bf16
        const unsigned short* xp = (const unsigned short*)x;
#pragma unroll 2
        for (int k0 = 0; k0 < 256; k0 += 32) {
            const int kb = k0 + lg * 8;
            s16x8 a[2], bh[4], bl[4];
#pragma unroll
            for (int m = 0; m < 2; ++m) a[m] = ld8u(xp + ar[m] * 256 + kb);
#pragma unroll
            for (int n = 0; n < 4; ++n) {
                bh[n] = ld8u(bth + (long long)bn[n] * 256 + kb);
                bl[n] = ld8u(btl + (long long)bn[n] * 256 + kb);
            }
#pragma unroll
            for (int m = 0; m < 2; ++m)
#pragma unroll
                for (int n = 0; n < 4; ++n) {
                    acc[m][n] = mfma16(a[m], bh[n], acc[m][n]);
                    acc[m][n] = mfma16(a[m], bl[n], acc[m][n]);
                }
        }
    } else {                                      // x is fp32: split hi/lo too
        const float* xp = (const float*)x;
#pragma unroll 2
        for (int k0 = 0; k0 < 256; k0 += 32) {
            const int kb = k0 + lg * 8;
            s16x8 ah[2], al[2], bh[4], bl[4];
#pragma unroll
            for (int m = 0; m < 2; ++m) cvt_hl(xp + ar[m] * 256 + kb, ah[m], al[m]);
#pragma unroll
            for (int n = 0; n < 4; ++n) {
                bh[n] = ld8u(bth + (long long)bn[n] * 256 + kb);
                bl[n] = ld8u(btl + (long long)bn[n] * 256 + kb);
            }
#pragma unroll
            for (int m = 0; m < 2; ++m)
#pragma unroll
                for (int n = 0; n < 4; ++n) {
                    acc[m][n] = mfma16(ah[m], bh[n], acc[m][n]);
                    acc[m][n] = mfma16(ah[m], bl[n], acc[m][n]);
                    acc[m][n] = mfma16(al[m], bh[n], acc[m][n]);
                }
        }
    }
    // epilogue: scale by dinv[row], pair even/odd cols via shfl, pack bf16
#pragma unroll
    for (int m = 0; m < 2; ++m)
#pragma unroll
        for (int n = 0; n < 4; ++n) {
            const int col = wc * 64 + n * 16 + l15;
#pragma unroll
            for (int r = 0; r < 4; ++r) {
                long long row = r0 + m * 16 + lg * 4 + r;
                float v = acc[m][n][r] * dinv[(row < N) ? row : (N - 1)];
                float p = __shfl_xor(v, 1);
                if (!(lane & 1) && row < N)
                    Cp[row * 64 + (col >> 1)] = pack2(v, p);
            }
        }
}

// ---- gemm2 (MFMA): [mu|lv](fp32) = ha[N,128](bf16) @ [Wmu;Wlv] + bias ------
// In-place over the ha panel (Mp): wc=0 waves write mu into the dwords that
// wc=1 waves read as A -> __syncthreads() between K-loop and epilogue.
__global__ __launch_bounds__(256, 4) void k_gemm2m(
    const unsigned short* __restrict__ hap,
    const unsigned short* __restrict__ bth,
    const unsigned short* __restrict__ btl,
    const void* bmu, const void* blv, const unsigned* __restrict__ det,
    float* __restrict__ outMu, float* __restrict__ outLv, int N) {
    const int lane = threadIdx.x & 63;
    const int wid  = threadIdx.x >> 6;
    const int wr = wid >> 1, wc = wid & 1;
    const int l15 = lane & 15, lg = lane >> 4;
    const long long r0 = (long long)blockIdx.x * 64 + wr * 32;
    long long ar[2];
#pragma unroll
    for (int m = 0; m < 2; ++m) {
        long long r = r0 + m * 16 + l15;
        ar[m] = (r < N) ? r : (N - 1);
    }
    int bn[4];
#pragma unroll
    for (int n = 0; n < 4; ++n) bn[n] = wc * 64 + n * 16 + l15;

    f32x4 acc[2][4] = {};
#pragma unroll
    for (int k0 = 0; k0 < 128; k0 += 32) {
        const int kb = k0 + lg * 8;
        s16x8 a[2], bh[4], bl[4];
#pragma unroll
        for (int m = 0; m < 2; ++m) a[m] = ld8u(hap + ar[m] * 128 + kb);
#pragma unroll
        for (int n = 0; n < 4; ++n) {
            bh[n] = ld8u(bth + (long long)bn[n] * 128 + kb);
            bl[n] = ld8u(btl + (long long)bn[n] * 128 + kb);
        }
#pragma unroll
        for (int m = 0; m < 2; ++m)
#pragma unroll
            for (int n = 0; n < 4; ++n) {
                acc[m][n] = mfma16(a[m], bh[n], acc[m][n]);
                acc[m][n] = mfma16(a[m], bl[n], acc[m][n]);
            }
    }
    __syncthreads();   // all A-reads done before any in-place mu write
    const unsigned wf = det[1];
#pragma unroll
    for (int m = 0; m < 2; ++m)
#pragma unroll
        for (int n = 0; n < 4; ++n) {
            const int col = wc * 64 + n * 16 + l15;
            const float bias = (col < 64) ? ldf(bmu, col, wf)
                                          : ldf(blv, col - 64, wf);
#pragma unroll
            for (int r = 0; r < 4; ++r) {
                long long row = r0 + m * 16 + lg * 4 + r;
                if (row < N) {
                    float v = acc[m][n][r] + bias;
                    if (col < 64) outMu[row * 64 + col] = v;
                    else          outLv[row * 64 + (col - 64)] = v;
                }
            }
        }
}

// ---- gather over pre-scaled bf16[N,128] panel ------------------------------
// out[node] = op( dinv[node] * (sum_{s in nbrs} h'[s] + h'[node]) )
// one wave/node, 2 cols/lane (1 dword), 8-way predicated unroll.
// pos = exclusive start (no longer mutated by CSR fill).
__global__ __launch_bounds__(256) void k_gather(const unsigned* __restrict__ hp,
                                                const int* __restrict__ srt,
                                                const int* __restrict__ cnt,
                                                const int* __restrict__ pos,
                                                const float* __restrict__ dinv,
                                                const void* bias, const unsigned* det,
                                                int leaky, int prescaleOut,
                                                unsigned* __restrict__ outp, int N) {
    int node = blockIdx.x * 4 + (threadIdx.x >> 6);
    if (node >= N) return;
    int lane = threadIdx.x & 63;
    int beg = pos[node];
    int end = beg + cnt[node];
    float dd = dinv[node];
    unsigned hv = hp[(long long)node * 64 + lane];
    float a0 = bf2f((unsigned short)(hv & 0xffffu));
    float a1 = bf2f((unsigned short)(hv >> 16));
    for (int q = beg; q < end; q += 8) {
        int s[8];
        unsigned v[8];
#pragma unroll
        for (int j = 0; j < 8; ++j) {
            int qq = q + j;
            s[j] = srt[(qq < end) ? qq : beg];   // loop entered => beg valid
        }
#pragma unroll
        for (int j = 0; j < 8; ++j)
            v[j] = hp[(long long)s[j] * 64 + lane];
#pragma unroll
        for (int j = 0; j < 8; ++j) {
            bool on = (q + j) < end;
            a0 += on ? bf2f((unsigned short)(v[j] & 0xffffu)) : 0.f;
            a1 += on ? bf2f((unsigned short)(v[j] >> 16)) : 0.f;
        }
    }
    a0 *= dd;
    a1 *= dd;
    if (bias) {
        a0 += ldf(bias, 2 * lane, det[1]);
        a1 += ldf(bias, 2 * lane + 1, det[1]);
    }
    if (leaky) {
        a0 = (a0 >= 0.f) ? a0 : 0.01f * a0;
        a1 = (a1 >= 0.f) ? a1 : 0.01f * a1;
    }
    if (prescaleOut) { a0 *= dd; a1 *= dd; }
    outp[(long long)node * 64 + lane] = pack2(a0, a1);
}

__global__ void k_sentinel(float* out, long long lvOff) {
    if (threadIdx.x == 0 && blockIdx.x == 0) {
        out[0] = 9.99e5f;
        out[lvOff] = 9.98e5f;
    }
}

extern "C" void kernel_launch(void* const* d_in, const int* in_sizes, int n_in,
                              void* d_out, int out_size, void* d_ws, size_t ws_size,
                              hipStream_t stream) {
    (void)out_size;
    const int N = 100000, E = 1600000;
    bool ok = (n_in == 8) && in_sizes[0] == 25600000 && in_sizes[1] == 3200000 &&
              in_sizes[2] == 32768 && in_sizes[3] == 128 &&
              in_sizes[4] == 8192 && in_sizes[5] == 64 &&
              in_sizes[6] == 8192 && in_sizes[7] == 64 &&
              ws_size >= (size_t)21 * 1024 * 1024;
    if (!ok) {
        k_sentinel<<<1, 64, 0, stream>>>((float*)d_out, (long long)N * 64);
        return;
    }
    const void* x   = d_in[0];
    const void* ei  = d_in[1];
    const void* W1  = d_in[2];
    const void* b1  = d_in[3];
    const void* Wmu = d_in[4];
    const void* bmu = d_in[5];
    const void* Wlv = d_in[6];
    const void* blv = d_in[7];

    char* w = (char*)d_ws;
    auto carve = [&](size_t bytes) {
        char* p = w;
        w += (bytes + 255) & ~(size_t)255;
        return p;
    };
    unsigned* flags = (unsigned*)carve(64);
    int*    cnt  = (int*)carve((size_t)N * 4);
    int*    pos  = (int*)carve((size_t)N * 4);
    float*  dinv = (float*)carve((size_t)N * 4);
    int*    bsum = (int*)carve(4096);
    int*    srt  = (int*)carve((size_t)E * 4);
    unsigned short* bt1h = (unsigned short*)carve(128 * 256 * 2);  // 64KB
    unsigned short* bt1l = (unsigned short*)carve(128 * 256 * 2);
    unsigned short* bt2h = (unsigned short*)carve(128 * 128 * 2);  // 32KB
    unsigned short* bt2l = (unsigned short*)carve(128 * 128 * 2);
    int*      btail  = (int*)carve((size_t)NBKT * 8 * 4);               // 25KB
    unsigned* bstore = (unsigned*)carve((size_t)NBKT * 8 * CAPS * 4);   // 12.8MB
    // total ~20.6MB

    float* M = (float*)d_out;                  // mu region / panel storage
    float* L = M + (size_t)N * 64;             // logvar region / panel storage
    unsigned* Mp = (unsigned*)M;               // bf16[N,128] as dword[N*64]
    unsigned* Lp = (unsigned*)L;

    const int nb = (N + 1023) / 1024;
    const int gblk = (N + 3) / 4;
    const int gb64 = (N + 63) / 64;            // 1563 (tail block: 32 rows)

    k_zero<<<1, 64, 0, stream>>>(flags, 16);
    k_detect<<<1, 256, 0, stream>>>(x, W1, ei, flags);
    k_zero<<<(NBKT * 8 + 255) / 256, 256, 0, stream>>>((unsigned*)btail, NBKT * 8);

    // bucketed counting sort (replaces k_count + k_fill)
    k_bucket<<<(E + 255) / 256, 256, 0, stream>>>(ei, flags, btail, bstore, E, N);
    k_bhist<<<NBKT, 256, 0, stream>>>(btail, bstore, cnt, N);
    k_dinv<<<(N + 255) / 256, 256, 0, stream>>>(cnt, dinv, N);
    k_scan_blk<<<nb, 256, 0, stream>>>(cnt, pos, bsum, N);
    k_scan_top<<<1, 64, 0, stream>>>(bsum, nb);
    k_scan_add<<<nb, 256, 0, stream>>>(pos, bsum, N);
    k_emit<<<NBKT, 256, 0, stream>>>(btail, bstore, pos, srt, N);

    // weight transpose + hi/lo split (tiny; L2-resident thereafter)
    k_wsplit<<<(256 * 128 + 255) / 256, 256, 0, stream>>>(W1, nullptr, flags, 256,
                                                          bt1h, bt1l);
    k_wsplit<<<(128 * 128 + 255) / 256, 256, 0, stream>>>(Wmu, Wlv, flags, 128,
                                                          bt2h, bt2l);

    // h0' = (x@W1) * dinv[row]  -> bf16 panel in M   (MFMA)
    k_gemm1m<<<gb64, 256, 0, stream>>>(x, flags, bt1h, bt1l, dinv, Mp, N);
    // h'  = leaky(dd*(sum+self) + b1) * dd -> bf16 panel in L
    k_gather<<<gblk, 256, 0, stream>>>(Mp, srt, cnt, pos, dinv, b1, flags, 1, 1,
                                       Lp, N);
    // ha  = dd*(sum+self) -> bf16 panel in M (h0' dead)
    k_gather<<<gblk, 256, 0, stream>>>(Lp, srt, cnt, pos, dinv, nullptr, flags,
                                       0, 0, Mp, N);
    // [mu|lv] = ha @ [Wmu;Wlv] + bias -> fp32 M/L in-place   (MFMA)
    k_gemm2m<<<gb64, 256, 0, stream>>>((const unsigned short*)Mp, bt2h, bt2l,
                                       bmu, blv, flags, M, L, N);
}

// Round 4
// 549.221 us; speedup vs baseline: 1.4226x; 1.0203x over previous
//
#include <hip/hip_runtime.h>

typedef unsigned short bf16_t;
typedef short s16x8 __attribute__((ext_vector_type(8)));
typedef float f32x4 __attribute__((ext_vector_type(4)));

// ===========================================================================
// Round 11 (R10 passed @560us). R10 profile: k_gemm1m = 107us top, MfmaUtil
// 7%, VALUBusy 14%, HBM 10% -- no pipe busy. Diagnosis: every frag load is
// 16 lanes x 16B at 512B stride = 16 scattered 64B lines per VMEM instr
// (A from HBM, B from L2); address/latency-bound at 6x the ~17us mem floor.
// Change: k_gemm1m -> k_gemm1s, m97-style LDS-staged GEMM:
//  - 128x128 block tile, 4 waves 2x2 (wave 64x64), BK=64, 2-barrier loop.
//  - A/Bh/Bl staged via global_load_lds width=16 (48KB LDS, 3 blocks/CU,
//    grid 782 fully resident).
//  - 128B LDS rows are bank-aligned -> piece rotation phys=(piece+row)&7,
//    applied on the per-lane GLOBAL source (m173 both-sides rule) and on
//    ds_read addr: uniform 8-lane/bank-group = b128 floor, no conflicts.
//  - per K-step: 12 ds_read_b128 + 32 MFMA (hi then lo B to cap VGPR).
//  - fp32-x fallback (det[0]) keeps old no-LDS path, correctness-only.
// k_gemm2m intentionally unchanged (isolate the variable).
// ===========================================================================

#define NBKT 782   // ceil(100000/128) buckets of 128 nodes
#define BSH  7
#define BMSK 127
#define CAPS 512   // per (bucket,sub) capacity: mean 256 + 16 sigma

__device__ __forceinline__ float bf2f(unsigned short u) {
    unsigned int v = ((unsigned int)u) << 16;
    float f;
    __builtin_memcpy(&f, &v, 4);
    return f;
}
__device__ __forceinline__ unsigned short f2bf(float f) {
    unsigned int x;
    __builtin_memcpy(&x, &f, 4);
    unsigned int r = x + 0x7fffu + ((x >> 16) & 1u);
    return (unsigned short)(r >> 16);
}
__device__ __forceinline__ unsigned pack2(float a, float b) {
    return (unsigned)f2bf(a) | ((unsigned)f2bf(b) << 16);
}
__device__ __forceinline__ float ldf(const void* p, long long i, unsigned f32) {
    return f32 ? ((const float*)p)[i] : bf2f(((const unsigned short*)p)[i]);
}
__device__ __forceinline__ int ldi(const void* p, long long i, unsigned i64) {
    return i64 ? (int)((const long long*)p)[i] : ((const int*)p)[i];
}
__device__ __forceinline__ s16x8 ld8u(const unsigned short* p) {
    return *(const s16x8*)p;   // 16B aligned at all call sites
}
__device__ __forceinline__ f32x4 mfma16(s16x8 a, s16x8 b, f32x4 c) {
    return __builtin_amdgcn_mfma_f32_16x16x32_bf16(a, b, c, 0, 0, 0);
}
__device__ __forceinline__ void gload16(const void* g, void* l) {
    __builtin_amdgcn_global_load_lds(
        (const __attribute__((address_space(1))) void*)g,
        (__attribute__((address_space(3))) void*)l, 16, 0, 0);
}
// fp32 -> (hi, lo) bf16 fragments, 8 consecutive floats
__device__ __forceinline__ void cvt_hl(const float* p, s16x8& hi, s16x8& lo) {
    const float4 u = *(const float4*)p;
    const float4 w = *(const float4*)(p + 4);
    float v[8] = {u.x, u.y, u.z, u.w, w.x, w.y, w.z, w.w};
#pragma unroll
    for (int j = 0; j < 8; ++j) {
        unsigned short h = f2bf(v[j]);
        hi[j] = (short)h;
        lo[j] = (short)f2bf(v[j] - bf2f(h));
    }
}

__global__ __launch_bounds__(256) void k_zero(unsigned* __restrict__ p, int n) {
    int i = blockIdx.x * 256 + threadIdx.x;
    if (i < n) p[i] = 0;
}

// ---- format detector: flags[0]=x_f32, flags[1]=W_f32, flags[2]=ei_i64 ------
__global__ __launch_bounds__(256) void k_detect(const void* x, const void* W1,
                                                const void* ei, unsigned* flags) {
    __shared__ float smx[256];
    __shared__ float smw[256];
    __shared__ int   szc[256];
    int tid = threadIdx.x;
    const unsigned short* xu = (const unsigned short*)x;
    float mx = 0.f;
    for (int i = tid; i < 4096; i += 256) {
        unsigned short w = xu[i];
        if ((w & 0x7fffu) >= 0x7f80u) mx = 1e30f;
        else { float f = fabsf(bf2f(w)); if (f > mx) mx = f; }
    }
    smx[tid] = mx;
    const unsigned short* wu = (const unsigned short*)W1;
    float mw = 0.f;
    for (int i = tid; i < 4096; i += 256) {
        unsigned short w = wu[i];
        if ((w & 0x7fffu) >= 0x7f80u) mw = 1e30f;
        else { float f = fabsf(bf2f(w)); if (f > mw) mw = f; }
    }
    smw[tid] = mw;
    const int* eu = (const int*)ei;
    int zc = 0;
    for (int i = tid; i < 128; i += 256)
        if ((i & 1) && eu[i] == 0) ++zc;
    szc[tid] = zc;
    __syncthreads();
    for (int off = 128; off > 0; off >>= 1) {
        if (tid < off) {
            if (smx[tid + off] > smx[tid]) smx[tid] = smx[tid + off];
            if (smw[tid + off] > smw[tid]) smw[tid] = smw[tid + off];
            szc[tid] += szc[tid + off];
        }
        __syncthreads();
    }
    if (tid == 0) {
        flags[0] = (smx[0] > 1e4f) ? 1u : 0u;
        flags[1] = (smw[0] > 10.f) ? 1u : 0u;
        flags[2] = (szc[0] >= 56) ? 1u : 0u;
    }
}

// ---- phase A: bucket scatter (append streams, XCD-local counters) ----------
__global__ __launch_bounds__(256) void k_bucket(const void* ei, const unsigned* det,
                                                int* __restrict__ btail,
                                                unsigned* __restrict__ bstore,
                                                int E, int N) {
    int e = blockIdx.x * 256 + threadIdx.x;
    if (e >= E) return;
    unsigned i64 = det[2];
    int s = ldi(ei, e, i64);
    int d = ldi(ei, (long long)E + e, i64);
    if ((unsigned)d >= (unsigned)N) return;
    int b = d >> BSH;
    int sub = blockIdx.x & 7;
    int slot = atomicAdd(&btail[sub * NBKT + b], 1);
    if (slot < CAPS) {
        unsigned src = ((unsigned)s < (unsigned)N) ? (unsigned)s : (unsigned)d;
        bstore[((long long)(b * 8 + sub)) * CAPS + slot] =
            ((unsigned)(d & BMSK) << 24) | src;
    }
}

// ---- phase B1: per-bucket histogram -> cnt (coalesced write) ---------------
__global__ __launch_bounds__(256) void k_bhist(const int* __restrict__ btail,
                                               const unsigned* __restrict__ bstore,
                                               int* __restrict__ cnt, int N) {
    __shared__ int lh[128];
    __shared__ int ln[8];
    const int b = blockIdx.x;
    const int tid = threadIdx.x;
    if (tid < 128) lh[tid] = 0;
    if (tid < 8) {
        int t = btail[tid * NBKT + b];
        ln[tid] = t < CAPS ? t : CAPS;
    }
    __syncthreads();
#pragma unroll 1
    for (int s = 0; s < 8; ++s) {
        int n = ln[s];
        const unsigned* base = &bstore[((long long)(b * 8 + s)) * CAPS];
        for (int i = tid; i < n; i += 256)
            atomicAdd(&lh[base[i] >> 24], 1);
    }
    __syncthreads();
    int node = b * 128 + tid;
    if (tid < 128 && node < N) cnt[node] = lh[tid];
}

__global__ __launch_bounds__(256) void k_dinv(const int* __restrict__ cnt,
                                              float* __restrict__ dinv, int N) {
    int i = blockIdx.x * 256 + threadIdx.x;
    if (i < N) dinv[i] = rsqrtf((float)cnt[i] + 1.0f);  // +1 self-loop
}

// ---- exclusive scan (3-phase) ----------------------------------------------
__global__ __launch_bounds__(256) void k_scan_blk(const int* __restrict__ cnt,
                                                  int* __restrict__ pos,
                                                  int* __restrict__ bsum, int N) {
    __shared__ int sh[256];
    const int tid = threadIdx.x;
    const int base = blockIdx.x * 1024 + tid * 4;
    int v[4];
#pragma unroll
    for (int j = 0; j < 4; ++j) v[j] = (base + j < N) ? cnt[base + j] : 0;
    int s = v[0] + v[1] + v[2] + v[3];
    sh[tid] = s;
    __syncthreads();
    for (int off = 1; off < 256; off <<= 1) {
        int t = (tid >= off) ? sh[tid - off] : 0;
        __syncthreads();
        sh[tid] += t;
        __syncthreads();
    }
    int run = sh[tid] - s;
#pragma unroll
    for (int j = 0; j < 4; ++j) {
        if (base + j < N) pos[base + j] = run;
        run += v[j];
    }
    if (tid == 255) bsum[blockIdx.x] = sh[255];
}

__global__ void k_scan_top(int* __restrict__ bsum, int nb) {
    if (threadIdx.x == 0 && blockIdx.x == 0) {
        int running = 0;
        for (int b = 0; b < nb; ++b) {
            int t = bsum[b];
            bsum[b] = running;
            running += t;
        }
    }
}

__global__ __launch_bounds__(256) void k_scan_add(int* __restrict__ pos,
                                                  const int* __restrict__ bsum, int N) {
    int add = bsum[blockIdx.x];
    int base = blockIdx.x * 1024;
    for (int i = threadIdx.x; i < 1024; i += 256)
        if (base + i < N) pos[base + i] += add;
}

// ---- phase B2: per-bucket placement + coalesced srt write ------------------
__global__ __launch_bounds__(256) void k_emit(const int* __restrict__ btail,
                                              const unsigned* __restrict__ bstore,
                                              const int* __restrict__ pos,
                                              int* __restrict__ srt, int N) {
    __shared__ int lstart[128];
    __shared__ int loff[128];
    __shared__ int ln[8];
    __shared__ int stage[4096];   // <= 8*CAPS
    const int b = blockIdx.x;
    const int tid = threadIdx.x;
    const int base0 = pos[b * 128];          // b*128 <= 99968 < N always
    if (tid < 128) {
        int node = b * 128 + tid;
        lstart[tid] = (node < N) ? (pos[node] - base0) : 0;
        loff[tid] = 0;
    }
    if (tid < 8) {
        int t = btail[tid * NBKT + b];
        ln[tid] = t < CAPS ? t : CAPS;
    }
    __syncthreads();
#pragma unroll 1
    for (int s = 0; s < 8; ++s) {
        int n = ln[s];
        const unsigned* bp = &bstore[((long long)(b * 8 + s)) * CAPS];
        for (int i = tid; i < n; i += 256) {
            unsigned rec = bp[i];
            int dl = rec >> 24;
            int slot = atomicAdd(&loff[dl], 1);
            stage[lstart[dl] + slot] = (int)(rec & 0xffffffu);
        }
    }
    __syncthreads();
    int total = ln[0] + ln[1] + ln[2] + ln[3] + ln[4] + ln[5] + ln[6] + ln[7];
    for (int i = tid; i < total; i += 256)
        srt[base0 + i] = stage[i];
}

// ---- weight transpose + hi/lo bf16 split -----------------------------------
// out BT_hi/BT_lo [128 n][K k] bf16; w ~= hi + lo to ~2^-17 relative.
// Wb==null: Wa is [K][128]. Wb!=null: cols 0..63 from Wa[K][64], 64..127 Wb.
__global__ __launch_bounds__(256) void k_wsplit(const void* Wa, const void* Wb,
                                                const unsigned* det, int K,
                                                unsigned short* __restrict__ bth,
                                                unsigned short* __restrict__ btl) {
    int idx = blockIdx.x * 256 + threadIdx.x;
    if (idx >= K * 128) return;
    int k = idx >> 7, n = idx & 127;
    unsigned wf = det[1];
    float w;
    if (Wb) w = (n < 64) ? ldf(Wa, (long long)k * 64 + n, wf)
                         : ldf(Wb, (long long)k * 64 + (n - 64), wf);
    else    w = ldf(Wa, idx, wf);
    unsigned short h = f2bf(w);
    bth[(long long)n * K + k] = h;
    btl[(long long)n * K + k] = f2bf(w - bf2f(h));
}

// ---- gemm1 (MFMA, LDS-staged): h0'[N,128](bf16) = (x@W1) * dinv[row] -------
// Block 128 rows x 128 cols; 4 waves 2x2; wave tile 64x64. BK=64, 4 chunks.
// A/Bh/Bl tiles [128][64] bf16 (128B rows) staged via global_load_lds w=16;
// piece rotation phys=(piece+row)&7 on global source + ds_read addr.
__global__ __launch_bounds__(256, 3) void k_gemm1s(
    const void* __restrict__ x, const unsigned* __restrict__ det,
    const unsigned short* __restrict__ bth,
    const unsigned short* __restrict__ btl,
    const float* __restrict__ dinv,
    unsigned* __restrict__ Cp, int N) {
    __shared__ unsigned short sA[128 * 64];   // 16 KB
    __shared__ unsigned short sBh[128 * 64];  // 16 KB
    __shared__ unsigned short sBl[128 * 64];  // 16 KB
    const int tid  = threadIdx.x;
    const int lane = tid & 63;
    const int wid  = tid >> 6;               // 0..3
    const int wr = wid >> 1, wc = wid & 1;
    const int l15 = lane & 15, lg = lane >> 4;   // lg 0..3
    const int rowbase = blockIdx.x * 128;

    f32x4 acc[4][4] = {};

    if (!det[0]) {                            // ---- bf16-x fast path ----
        const unsigned short* xp = (const unsigned short*)x;
        const int sr8 = lane >> 3;            // row-in-issue 0..7
        const int sp  = lane & 7;             // physical piece 0..7
#pragma unroll 1
        for (int k0 = 0; k0 < 256; k0 += 64) {
            // stage A: wave w covers rows [w*32, w*32+32)
#pragma unroll
            for (int q = 0; q < 4; ++q) {
                int r = wid * 32 + q * 8 + sr8;          // tile row 0..127
                int grow = rowbase + r;
                if (grow >= N) grow = N - 1;             // tail clamp
                int c = (sp - r) & 7;                    // data piece at phys sp
                gload16(xp + (long long)grow * 256 + k0 + c * 8,
                        &sA[(wid * 32 + q * 8) * 64]);
            }
            // stage Bh, Bl: rows = output cols 0..127
#pragma unroll
            for (int q = 0; q < 4; ++q) {
                int r = wid * 32 + q * 8 + sr8;
                int c = (sp - r) & 7;
                long long goff = (long long)r * 256 + k0 + c * 8;
                gload16(bth + goff, &sBh[(wid * 32 + q * 8) * 64]);
                gload16(btl + goff, &sBl[(wid * 32 + q * 8) * 64]);
            }
            __syncthreads();   // compiler drains vmcnt before s_barrier
#pragma unroll
            for (int kk = 0; kk < 2; ++kk) {
                const int cbase = kk * 4 + lg;           // data piece 0..7
                s16x8 a[4], b[4];
#pragma unroll
                for (int m = 0; m < 4; ++m) {
                    int lrow = wr * 64 + m * 16 + l15;
                    int p = (cbase + lrow) & 7;
                    a[m] = ld8u(&sA[lrow * 64 + p * 8]);
                }
#pragma unroll
                for (int n = 0; n < 4; ++n) {
                    int lcol = wc * 64 + n * 16 + l15;
                    int p = (cbase + lcol) & 7;
                    b[n] = ld8u(&sBh[lcol * 64 + p * 8]);
                }
#pragma unroll
                for (int m = 0; m < 4; ++m)
#pragma unroll
                    for (int n = 0; n < 4; ++n)
                        acc[m][n] = mfma16(a[m], b[n], acc[m][n]);
#pragma unroll
                for (int n = 0; n < 4; ++n) {
                    int lcol = wc * 64 + n * 16 + l15;
                    int p = (cbase + lcol) & 7;
                    b[n] = ld8u(&sBl[lcol * 64 + p * 8]);
                }
#pragma unroll
                for (int m = 0; m < 4; ++m)
#pragma unroll
                    for (int n = 0; n < 4; ++n)
                        acc[m][n] = mfma16(a[m], b[n], acc[m][n]);
            }
            __syncthreads();
        }
    } else {                                  // ---- fp32-x fallback (slow) --
        const float* xpf = (const float*)x;
        long long ar[4];
#pragma unroll
        for (int m = 0; m < 4; ++m) {
            long long r = rowbase + wr * 64 + m * 16 + l15;
            ar[m] = (r < N) ? r : (N - 1);
        }
        int bn[4];
#pragma unroll
        for (int n = 0; n < 4; ++n) bn[n] = wc * 64 + n * 16 + l15;
#pragma unroll 1
        for (int k0 = 0; k0 < 256; k0 += 32) {
            const int kb = k0 + lg * 8;
            s16x8 ah[4], al[4], b[4];
#pragma unroll
            for (int m = 0; m < 4; ++m) cvt_hl(xpf + ar[m] * 256 + kb, ah[m], al[m]);
#pragma unroll
            for (int n = 0; n < 4; ++n) b[n] = ld8u(bth + (long long)bn[n] * 256 + kb);
#pragma unroll
            for (int m = 0; m < 4; ++m)
#pragma unroll
                for (int n = 0; n < 4; ++n) {
                    acc[m][n] = mfma16(ah[m], b[n], acc[m][n]);
                    acc[m][n] = mfma16(al[m], b[n], acc[m][n]);
                }
#pragma unroll
            for (int n = 0; n < 4; ++n) b[n] = ld8u(btl + (long long)bn[n] * 256 + kb);
#pragma unroll
            for (int m = 0; m < 4; ++m)
#pragma unroll
                for (int n = 0; n < 4; ++n)
                    acc[m][n] = mfma16(ah[m], b[n], acc[m][n]);
        }
    }

    // epilogue: scale by dinv[row], pair even/odd cols via shfl, pack bf16
#pragma unroll
    for (int m = 0; m < 4; ++m)
#pragma unroll
        for (int n = 0; n < 4; ++n) {
            const int col = wc * 64 + n * 16 + l15;
#pragma unroll
            for (int r = 0; r < 4; ++r) {
                int row = rowbase + wr * 64 + m * 16 + lg * 4 + r;
                float v = acc[m][n][r] * dinv[(row < N) ? row : (N - 1)];
                float p = __shfl_xor(v, 1);
                if (!(lane & 1) && row < N)
                    Cp[(long long)row * 64 + (col >> 1)] = pack2(v, p);
            }
        }
}

// ---- gemm2 (MFMA): [mu|lv](fp32) = ha[N,128](bf16) @ [Wmu;Wlv] + bias ------
// In-place over the ha panel (Mp): wc=0 waves write mu into the dwords that
// wc=1 waves read as A -> __syncthreads() between K-loop and epilogue.
__global__ __launch_bounds__(256, 4) void k_gemm2m(
    const unsigned short* __restrict__ hap,
    const unsigned short* __restrict__ bth,
    const unsigned short* __restrict__ btl,
    const void* bmu, const void* blv, const unsigned* __restrict__ det,
    float* __restrict__ outMu, float* __restrict__ outLv, int N) {
    const int lane = threadIdx.x & 63;
    const int wid  = threadIdx.x >> 6;
    const int wr = wid >> 1, wc = wid & 1;
    const int l15 = lane & 15, lg = lane >> 4;
    const long long r0 = (long long)blockIdx.x * 64 + wr * 32;
    long long ar[2];
#pragma unroll
    for (int m = 0; m < 2; ++m) {
        long long r = r0 + m * 16 + l15;
        ar[m] = (r < N) ? r : (N - 1);
    }
    int bn[4];
#pragma unroll
    for (int n = 0; n < 4; ++n) bn[n] = wc * 64 + n * 16 + l15;

    f32x4 acc[2][4] = {};
#pragma unroll
    for (int k0 = 0; k0 < 128; k0 += 32) {
        const int kb = k0 + lg * 8;
        s16x8 a[2], bh[4], bl[4];
#pragma unroll
        for (int m = 0; m < 2; ++m) a[m] = ld8u(hap + ar[m] * 128 + kb);
#pragma unroll
        for (int n = 0; n < 4; ++n) {
            bh[n] = ld8u(bth + (long long)bn[n] * 128 + kb);
            bl[n] = ld8u(btl + (long long)bn[n] * 128 + kb);
        }
#pragma unroll
        for (int m = 0; m < 2; ++m)
#pragma unroll
            for (int n = 0; n < 4; ++n) {
                acc[m][n] = mfma16(a[m], bh[n], acc[m][n]);
                acc[m][n] = mfma16(a[m], bl[n], acc[m][n]);
            }
    }
    __syncthreads();   // all A-reads done before any in-place mu write
    const unsigned wf = det[1];
#pragma unroll
    for (int m = 0; m < 2; ++m)
#pragma unroll
        for (int n = 0; n < 4; ++n) {
            const int col = wc * 64 + n * 16 + l15;
            const float bias = (col < 64) ? ldf(bmu, col, wf)
                                          : ldf(blv, col - 64, wf);
#pragma unroll
            for (int r = 0; r < 4; ++r) {
                long long row = r0 + m * 16 + lg * 4 + r;
                if (row < N) {
                    float v = acc[m][n][r] + bias;
                    if (col < 64) outMu[row * 64 + col] = v;
                    else          outLv[row * 64 + (col - 64)] = v;
                }
            }
        }
}

// ---- gather over pre-scaled bf16[N,128] panel ------------------------------
// out[node] = op( dinv[node] * (sum_{s in nbrs} h'[s] + h'[node]) )
// one wave/node, 2 cols/lane (1 dword), 8-way predicated unroll.
// pos = exclusive start (not mutated by CSR build).
__global__ __launch_bounds__(256) void k_gather(const unsigned* __restrict__ hp,
                                                const int* __restrict__ srt,
                                                const int* __restrict__ cnt,
                                                const int* __restrict__ pos,
                                                const float* __restrict__ dinv,
                                                const void* bias, const unsigned* det,
                                                int leaky, int prescaleOut,
                                                unsigned* __restrict__ outp, int N) {
    int node = blockIdx.x * 4 + (threadIdx.x >> 6);
    if (node >= N) return;
    int lane = threadIdx.x & 63;
    int beg = pos[node];
    int end = beg + cnt[node];
    float dd = dinv[node];
    unsigned hv = hp[(long long)node * 64 + lane];
    float a0 = bf2f((unsigned short)(hv & 0xffffu));
    float a1 = bf2f((unsigned short)(hv >> 16));
    for (int q = beg; q < end; q += 8) {
        int s[8];
        unsigned v[8];
#pragma unroll
        for (int j = 0; j < 8; ++j) {
            int qq = q + j;
            s[j] = srt[(qq < end) ? qq : beg];   // loop entered => beg valid
        }
#pragma unroll
        for (int j = 0; j < 8; ++j)
            v[j] = hp[(long long)s[j] * 64 + lane];
#pragma unroll
        for (int j = 0; j < 8; ++j) {
            bool on = (q + j) < end;
            a0 += on ? bf2f((unsigned short)(v[j] & 0xffffu)) : 0.f;
            a1 += on ? bf2f((unsigned short)(v[j] >> 16)) : 0.f;
        }
    }
    a0 *= dd;
    a1 *= dd;
    if (bias) {
        a0 += ldf(bias, 2 * lane, det[1]);
        a1 += ldf(bias, 2 * lane + 1, det[1]);
    }
    if (leaky) {
        a0 = (a0 >= 0.f) ? a0 : 0.01f * a0;
        a1 = (a1 >= 0.f) ? a1 : 0.01f * a1;
    }
    if (prescaleOut) { a0 *= dd; a1 *= dd; }
    outp[(long long)node * 64 + lane] = pack2(a0, a1);
}

__global__ void k_sentinel(float* out, long long lvOff) {
    if (threadIdx.x == 0 && blockIdx.x == 0) {
        out[0] = 9.99e5f;
        out[lvOff] = 9.98e5f;
    }
}

extern "C" void kernel_launch(void* const* d_in, const int* in_sizes, int n_in,
                              void* d_out, int out_size, void* d_ws, size_t ws_size,
                              hipStream_t stream) {
    (void)out_size;
    const int N = 100000, E = 1600000;
    bool ok = (n_in == 8) && in_sizes[0] == 25600000 && in_sizes[1] == 3200000 &&
              in_sizes[2] == 32768 && in_sizes[3] == 128 &&
              in_sizes[4] == 8192 && in_sizes[5] == 64 &&
              in_sizes[6] == 8192 && in_sizes[7] == 64 &&
              ws_size >= (size_t)21 * 1024 * 1024;
    if (!ok) {
        k_sentinel<<<1, 64, 0, stream>>>((float*)d_out, (long long)N * 64);
        return;
    }
    const void* x   = d_in[0];
    const void* ei  = d_in[1];
    const void* W1  = d_in[2];
    const void* b1  = d_in[3];
    const void* Wmu = d_in[4];
    const void* bmu = d_in[5];
    const void* Wlv = d_in[6];
    const void* blv = d_in[7];

    char* w = (char*)d_ws;
    auto carve = [&](size_t bytes) {
        char* p = w;
        w += (bytes + 255) & ~(size_t)255;
        return p;
    };
    unsigned* flags = (unsigned*)carve(64);
    int*    cnt  = (int*)carve((size_t)N * 4);
    int*    pos  = (int*)carve((size_t)N * 4);
    float*  dinv = (float*)carve((size_t)N * 4);
    int*    bsum = (int*)carve(4096);
    int*    srt  = (int*)carve((size_t)E * 4);
    unsigned short* bt1h = (unsigned short*)carve(128 * 256 * 2);  // 64KB
    unsigned short* bt1l = (unsigned short*)carve(128 * 256 * 2);
    unsigned short* bt2h = (unsigned short*)carve(128 * 128 * 2);  // 32KB
    unsigned short* bt2l = (unsigned short*)carve(128 * 128 * 2);
    int*      btail  = (int*)carve((size_t)NBKT * 8 * 4);               // 25KB
    unsigned* bstore = (unsigned*)carve((size_t)NBKT * 8 * CAPS * 4);   // 12.8MB
    // total ~20.6MB

    float* M = (float*)d_out;                  // mu region / panel storage
    float* L = M + (size_t)N * 64;             // logvar region / panel storage
    unsigned* Mp = (unsigned*)M;               // bf16[N,128] as dword[N*64]
    unsigned* Lp = (unsigned*)L;

    const int nb = (N + 1023) / 1024;
    const int gblk = (N + 3) / 4;
    const int gb64  = (N + 63) / 64;           // gemm2 grid
    const int gb128 = (N + 127) / 128;         // gemm1 grid (782)

    k_zero<<<1, 64, 0, stream>>>(flags, 16);
    k_detect<<<1, 256, 0, stream>>>(x, W1, ei, flags);
    k_zero<<<(NBKT * 8 + 255) / 256, 256, 0, stream>>>((unsigned*)btail, NBKT * 8);

    // bucketed counting sort (replaces k_count + k_fill)
    k_bucket<<<(E + 255) / 256, 256, 0, stream>>>(ei, flags, btail, bstore, E, N);
    k_bhist<<<NBKT, 256, 0, stream>>>(btail, bstore, cnt, N);
    k_dinv<<<(N + 255) / 256, 256, 0, stream>>>(cnt, dinv, N);
    k_scan_blk<<<nb, 256, 0, stream>>>(cnt, pos, bsum, N);
    k_scan_top<<<1, 64, 0, stream>>>(bsum, nb);
    k_scan_add<<<nb, 256, 0, stream>>>(pos, bsum, N);
    k_emit<<<NBKT, 256, 0, stream>>>(btail, bstore, pos, srt, N);

    // weight transpose + hi/lo split (tiny; L2-resident thereafter)
    k_wsplit<<<(256 * 128 + 255) / 256, 256, 0, stream>>>(W1, nullptr, flags, 256,
                                                          bt1h, bt1l);
    k_wsplit<<<(128 * 128 + 255) / 256, 256, 0, stream>>>(Wmu, Wlv, flags, 128,
                                                          bt2h, bt2l);

    // h0' = (x@W1) * dinv[row]  -> bf16 panel in M   (MFMA, LDS-staged)
    k_gemm1s<<<gb128, 256, 0, stream>>>(x, flags, bt1h, bt1l, dinv, Mp, N);
    // h'  = leaky(dd*(sum+self) + b1) * dd -> bf16 panel in L
    k_gather<<<gblk, 256, 0, stream>>>(Mp, srt, cnt, pos, dinv, b1, flags, 1, 1,
                                       Lp, N);
    // ha  = dd*(sum+self) -> bf16 panel in M (h0' dead)
    k_gather<<<gblk, 256, 0, stream>>>(Lp, srt, cnt, pos, dinv, nullptr, flags,
                                       0, 0, Mp, N);
    // [mu|lv] = ha @ [Wmu;Wlv] + bias -> fp32 M/L in-place   (MFMA)
    k_gemm2m<<<gb64, 256, 0, stream>>>((const unsigned short*)Mp, bt2h, bt2l,
                                       bmu, blv, flags, M, L, N);
}

// Round 5
// 527.289 us; speedup vs baseline: 1.4818x; 1.0416x over previous
//
#include <hip/hip_runtime.h>

typedef unsigned short bf16_t;
typedef short s16x8 __attribute__((ext_vector_type(8)));
typedef float f32x4 __attribute__((ext_vector_type(4)));

// ===========================================================================
// Round 12 (R11 passed @549us). R11 post-mortem: LDS-staged gemm1 (102us) ==
// no-LDS gemm1 (107us) despite opposite structures; FETCH/WRITE exactly
// logical bytes, 0 bank conflicts, MfmaUtil 7%, VALU 15%, HBM 10%, Occ 21%.
// Diagnosis: EXPOSED LATENCY -- in both variants step k+1's loads issue only
// after step k's MFMAs (barrier / no compiler pipelining at VGPR=64).
// Changes:
//  - k_gemm1p/k_gemm2p: no-LDS + explicit register pipeline, full static
//    unroll: A prefetched 2 steps ahead (HBM ~900cy), B 1 step (L2 ~200cy).
//    Discriminating test: ~50us => latency theory right; ~100us => stop.
//  - k_gather: 2 nodes/wave (32 lanes x uint2): 16 rows in flight/wave (2x),
//    half the load instructions.
//  - dispatch fusion 17->11: detect+=btail-zero (k_zero dropped; cnt no
//    longer needs zeroing -- bhist overwrites), bhist+=dinv, scan_top folded
//    into scan_add, wsplit merged into one dispatch.
// ===========================================================================

#define NBKT 782   // ceil(100000/128) buckets of 128 nodes
#define BSH  7
#define BMSK 127
#define CAPS 512   // per (bucket,sub) capacity: mean 256 + 16 sigma

__device__ __forceinline__ float bf2f(unsigned short u) {
    unsigned int v = ((unsigned int)u) << 16;
    float f;
    __builtin_memcpy(&f, &v, 4);
    return f;
}
__device__ __forceinline__ unsigned short f2bf(float f) {
    unsigned int x;
    __builtin_memcpy(&x, &f, 4);
    unsigned int r = x + 0x7fffu + ((x >> 16) & 1u);
    return (unsigned short)(r >> 16);
}
__device__ __forceinline__ unsigned pack2(float a, float b) {
    return (unsigned)f2bf(a) | ((unsigned)f2bf(b) << 16);
}
__device__ __forceinline__ float ldf(const void* p, long long i, unsigned f32) {
    return f32 ? ((const float*)p)[i] : bf2f(((const unsigned short*)p)[i]);
}
__device__ __forceinline__ int ldi(const void* p, long long i, unsigned i64) {
    return i64 ? (int)((const long long*)p)[i] : ((const int*)p)[i];
}
__device__ __forceinline__ s16x8 ld8u(const unsigned short* p) {
    return *(const s16x8*)p;   // 16B aligned at all call sites
}
__device__ __forceinline__ f32x4 mfma16(s16x8 a, s16x8 b, f32x4 c) {
    return __builtin_amdgcn_mfma_f32_16x16x32_bf16(a, b, c, 0, 0, 0);
}
// fp32 -> (hi, lo) bf16 fragments, 8 consecutive floats
__device__ __forceinline__ void cvt_hl(const float* p, s16x8& hi, s16x8& lo) {
    const float4 u = *(const float4*)p;
    const float4 w = *(const float4*)(p + 4);
    float v[8] = {u.x, u.y, u.z, u.w, w.x, w.y, w.z, w.w};
#pragma unroll
    for (int j = 0; j < 8; ++j) {
        unsigned short h = f2bf(v[j]);
        hi[j] = (short)h;
        lo[j] = (short)f2bf(v[j] - bf2f(h));
    }
}

// ---- detector + btail zero: flags[0]=x_f32, flags[1]=W_f32, flags[2]=ei_i64
__global__ __launch_bounds__(256) void k_detect(const void* x, const void* W1,
                                                const void* ei, unsigned* flags,
                                                int* __restrict__ btail) {
    __shared__ float smx[256];
    __shared__ float smw[256];
    __shared__ int   szc[256];
    int tid = threadIdx.x;
    for (int i = tid; i < NBKT * 8; i += 256) btail[i] = 0;
    const unsigned short* xu = (const unsigned short*)x;
    float mx = 0.f;
    for (int i = tid; i < 4096; i += 256) {
        unsigned short w = xu[i];
        if ((w & 0x7fffu) >= 0x7f80u) mx = 1e30f;
        else { float f = fabsf(bf2f(w)); if (f > mx) mx = f; }
    }
    smx[tid] = mx;
    const unsigned short* wu = (const unsigned short*)W1;
    float mw = 0.f;
    for (int i = tid; i < 4096; i += 256) {
        unsigned short w = wu[i];
        if ((w & 0x7fffu) >= 0x7f80u) mw = 1e30f;
        else { float f = fabsf(bf2f(w)); if (f > mw) mw = f; }
    }
    smw[tid] = mw;
    const int* eu = (const int*)ei;
    int zc = 0;
    for (int i = tid; i < 128; i += 256)
        if ((i & 1) && eu[i] == 0) ++zc;
    szc[tid] = zc;
    __syncthreads();
    for (int off = 128; off > 0; off >>= 1) {
        if (tid < off) {
            if (smx[tid + off] > smx[tid]) smx[tid] = smx[tid + off];
            if (smw[tid + off] > smw[tid]) smw[tid] = smw[tid + off];
            szc[tid] += szc[tid + off];
        }
        __syncthreads();
    }
    if (tid == 0) {
        flags[0] = (smx[0] > 1e4f) ? 1u : 0u;
        flags[1] = (smw[0] > 10.f) ? 1u : 0u;
        flags[2] = (szc[0] >= 56) ? 1u : 0u;
    }
}

// ---- phase A: bucket scatter (append streams, XCD-local counters) ----------
__global__ __launch_bounds__(256) void k_bucket(const void* ei, const unsigned* det,
                                                int* __restrict__ btail,
                                                unsigned* __restrict__ bstore,
                                                int E, int N) {
    int e = blockIdx.x * 256 + threadIdx.x;
    if (e >= E) return;
    unsigned i64 = det[2];
    int s = ldi(ei, e, i64);
    int d = ldi(ei, (long long)E + e, i64);
    if ((unsigned)d >= (unsigned)N) return;
    int b = d >> BSH;
    int sub = blockIdx.x & 7;
    int slot = atomicAdd(&btail[sub * NBKT + b], 1);
    if (slot < CAPS) {
        unsigned src = ((unsigned)s < (unsigned)N) ? (unsigned)s : (unsigned)d;
        bstore[((long long)(b * 8 + sub)) * CAPS + slot] =
            ((unsigned)(d & BMSK) << 24) | src;
    }
}

// ---- phase B1: per-bucket histogram -> cnt + dinv (coalesced) --------------
__global__ __launch_bounds__(256) void k_bhist(const int* __restrict__ btail,
                                               const unsigned* __restrict__ bstore,
                                               int* __restrict__ cnt,
                                               float* __restrict__ dinv, int N) {
    __shared__ int lh[128];
    __shared__ int ln[8];
    const int b = blockIdx.x;
    const int tid = threadIdx.x;
    if (tid < 128) lh[tid] = 0;
    if (tid < 8) {
        int t = btail[tid * NBKT + b];
        ln[tid] = t < CAPS ? t : CAPS;
    }
    __syncthreads();
#pragma unroll 1
    for (int s = 0; s < 8; ++s) {
        int n = ln[s];
        const unsigned* base = &bstore[((long long)(b * 8 + s)) * CAPS];
        for (int i = tid; i < n; i += 256)
            atomicAdd(&lh[base[i] >> 24], 1);
    }
    __syncthreads();
    int node = b * 128 + tid;
    if (tid < 128 && node < N) {
        cnt[node] = lh[tid];
        dinv[node] = rsqrtf((float)lh[tid] + 1.0f);  // +1 self-loop
    }
}

// ---- exclusive scan (2 dispatches) -----------------------------------------
__global__ __launch_bounds__(256) void k_scan_blk(const int* __restrict__ cnt,
                                                  int* __restrict__ pos,
                                                  int* __restrict__ bsum, int N) {
    __shared__ int sh[256];
    const int tid = threadIdx.x;
    const int base = blockIdx.x * 1024 + tid * 4;
    int v[4];
#pragma unroll
    for (int j = 0; j < 4; ++j) v[j] = (base + j < N) ? cnt[base + j] : 0;
    int s = v[0] + v[1] + v[2] + v[3];
    sh[tid] = s;
    __syncthreads();
    for (int off = 1; off < 256; off <<= 1) {
        int t = (tid >= off) ? sh[tid - off] : 0;
        __syncthreads();
        sh[tid] += t;
        __syncthreads();
    }
    int run = sh[tid] - s;
#pragma unroll
    for (int j = 0; j < 4; ++j) {
        if (base + j < N) pos[base + j] = run;
        run += v[j];
    }
    if (tid == 255) bsum[blockIdx.x] = sh[255];
}

// scan_top folded in: each block sums bsum[0..blockIdx) itself (<=97 reads).
__global__ __launch_bounds__(256) void k_scan_add(int* __restrict__ pos,
                                                  const int* __restrict__ bsum, int N) {
    __shared__ int sadd;
    if (threadIdx.x == 0) {
        int a = 0;
        for (int i = 0; i < blockIdx.x; ++i) a += bsum[i];
        sadd = a;
    }
    __syncthreads();
    int add = sadd;
    int base = blockIdx.x * 1024;
    for (int i = threadIdx.x; i < 1024; i += 256)
        if (base + i < N) pos[base + i] += add;
}

// ---- phase B2: per-bucket placement + coalesced srt write ------------------
__global__ __launch_bounds__(256) void k_emit(const int* __restrict__ btail,
                                              const unsigned* __restrict__ bstore,
                                              const int* __restrict__ pos,
                                              int* __restrict__ srt, int N) {
    __shared__ int lstart[128];
    __shared__ int loff[128];
    __shared__ int ln[8];
    __shared__ int stage[4096];   // <= 8*CAPS
    const int b = blockIdx.x;
    const int tid = threadIdx.x;
    const int base0 = pos[b * 128];          // b*128 <= 99968 < N always
    if (tid < 128) {
        int node = b * 128 + tid;
        lstart[tid] = (node < N) ? (pos[node] - base0) : 0;
        loff[tid] = 0;
    }
    if (tid < 8) {
        int t = btail[tid * NBKT + b];
        ln[tid] = t < CAPS ? t : CAPS;
    }
    __syncthreads();
#pragma unroll 1
    for (int s = 0; s < 8; ++s) {
        int n = ln[s];
        const unsigned* bp = &bstore[((long long)(b * 8 + s)) * CAPS];
        for (int i = tid; i < n; i += 256) {
            unsigned rec = bp[i];
            int dl = rec >> 24;
            int slot = atomicAdd(&loff[dl], 1);
            stage[lstart[dl] + slot] = (int)(rec & 0xffffffu);
        }
    }
    __syncthreads();
    int total = ln[0] + ln[1] + ln[2] + ln[3] + ln[4] + ln[5] + ln[6] + ln[7];
    for (int i = tid; i < total; i += 256)
        srt[base0 + i] = stage[i];
}

// ---- weight transpose + hi/lo bf16 split (both layers, one dispatch) -------
__global__ __launch_bounds__(256) void k_wsplit(const void* W1, const void* Wmu,
                                                const void* Wlv, const unsigned* det,
                                                unsigned short* __restrict__ bt1h,
                                                unsigned short* __restrict__ bt1l,
                                                unsigned short* __restrict__ bt2h,
                                                unsigned short* __restrict__ bt2l) {
    int idx = blockIdx.x * 256 + threadIdx.x;
    unsigned wf = det[1];
    if (idx < 256 * 128) {
        int k = idx >> 7, n = idx & 127;
        float w = ldf(W1, idx, wf);
        unsigned short h = f2bf(w);
        bt1h[(long long)n * 256 + k] = h;
        bt1l[(long long)n * 256 + k] = f2bf(w - bf2f(h));
    } else if (idx < 256 * 128 + 128 * 128) {
        int j = idx - 256 * 128;
        int k = j >> 7, n = j & 127;
        float w = (n < 64) ? ldf(Wmu, (long long)k * 64 + n, wf)
                           : ldf(Wlv, (long long)k * 64 + (n - 64), wf);
        unsigned short h = f2bf(w);
        bt2h[(long long)n * 128 + k] = h;
        bt2l[(long long)n * 128 + k] = f2bf(w - bf2f(h));
    }
}

// ---- gemm1 (MFMA, register-pipelined): h0' = (x@W1)*dinv ------------------
// 64 rows x 128 cols/block; 4 waves 2x2; wave 32x64 = 2x4 frags. 8 K-steps,
// fully unrolled; A prefetch 2 steps ahead (HBM), B 1 step ahead (L2).
__global__ __launch_bounds__(256, 2) void k_gemm1p(
    const void* __restrict__ x, const unsigned* __restrict__ det,
    const unsigned short* __restrict__ bth,
    const unsigned short* __restrict__ btl,
    const float* __restrict__ dinv,
    unsigned* __restrict__ Cp, int N) {
    const int lane = threadIdx.x & 63;
    const int wid  = threadIdx.x >> 6;
    const int wr = wid >> 1, wc = wid & 1;
    const int l15 = lane & 15, lg = lane >> 4;
    const long long r0 = (long long)blockIdx.x * 64 + wr * 32;
    long long ar[2];
#pragma unroll
    for (int m = 0; m < 2; ++m) {
        long long r = r0 + m * 16 + l15;
        ar[m] = (r < N) ? r : (N - 1);
    }
    int bn[4];
#pragma unroll
    for (int n = 0; n < 4; ++n) bn[n] = wc * 64 + n * 16 + l15;

    f32x4 acc[2][4] = {};
    if (!det[0]) {                                // x is bf16
        const unsigned short* xp = (const unsigned short*)x;
        const unsigned short* aP[2];
#pragma unroll
        for (int m = 0; m < 2; ++m) aP[m] = xp + ar[m] * 256 + lg * 8;
        const unsigned short* bHp[4];
        const unsigned short* bLp[4];
#pragma unroll
        for (int n = 0; n < 4; ++n) {
            bHp[n] = bth + (long long)bn[n] * 256 + lg * 8;
            bLp[n] = btl + (long long)bn[n] * 256 + lg * 8;
        }
        s16x8 aS[8][2], bhS[2][4], blS[2][4];
#pragma unroll
        for (int s = 0; s < 2; ++s)
#pragma unroll
            for (int m = 0; m < 2; ++m) aS[s][m] = ld8u(aP[m] + s * 32);
#pragma unroll
        for (int n = 0; n < 4; ++n) {
            bhS[0][n] = ld8u(bHp[n]);
            blS[0][n] = ld8u(bLp[n]);
        }
#pragma unroll
        for (int st = 0; st < 8; ++st) {
            if (st < 7) {
                const int nb = (st + 1) & 1;
#pragma unroll
                for (int n = 0; n < 4; ++n) {
                    bhS[nb][n] = ld8u(bHp[n] + (st + 1) * 32);
                    blS[nb][n] = ld8u(bLp[n] + (st + 1) * 32);
                }
            }
            if (st < 6) {
#pragma unroll
                for (int m = 0; m < 2; ++m)
                    aS[st + 2][m] = ld8u(aP[m] + (st + 2) * 32);
            }
            const int cb = st & 1;
#pragma unroll
            for (int m = 0; m < 2; ++m)
#pragma unroll
                for (int n = 0; n < 4; ++n) {
                    acc[m][n] = mfma16(aS[st][m], bhS[cb][n], acc[m][n]);
                    acc[m][n] = mfma16(aS[st][m], blS[cb][n], acc[m][n]);
                }
        }
    } else {                                      // x is fp32: split hi/lo too
        const float* xp = (const float*)x;
#pragma unroll 2
        for (int k0 = 0; k0 < 256; k0 += 32) {
            const int kb = k0 + lg * 8;
            s16x8 ah[2], al[2], bh[4], bl[4];
#pragma unroll
            for (int m = 0; m < 2; ++m) cvt_hl(xp + ar[m] * 256 + kb, ah[m], al[m]);
#pragma unroll
            for (int n = 0; n < 4; ++n) {
                bh[n] = ld8u(bth + (long long)bn[n] * 256 + kb);
                bl[n] = ld8u(btl + (long long)bn[n] * 256 + kb);
            }
#pragma unroll
            for (int m = 0; m < 2; ++m)
#pragma unroll
                for (int n = 0; n < 4; ++n) {
                    acc[m][n] = mfma16(ah[m], bh[n], acc[m][n]);
                    acc[m][n] = mfma16(ah[m], bl[n], acc[m][n]);
                    acc[m][n] = mfma16(al[m], bh[n], acc[m][n]);
                }
        }
    }
    // epilogue: scale by dinv[row], pair even/odd cols via shfl, pack bf16
#pragma unroll
    for (int m = 0; m < 2; ++m)
#pragma unroll
        for (int n = 0; n < 4; ++n) {
            const int col = wc * 64 + n * 16 + l15;
#pragma unroll
            for (int r = 0; r < 4; ++r) {
                long long row = r0 + m * 16 + lg * 4 + r;
                float v = acc[m][n][r] * dinv[(row < N) ? row : (N - 1)];
                float p = __shfl_xor(v, 1);
                if (!(lane & 1) && row < N)
                    Cp[row * 64 + (col >> 1)] = pack2(v, p);
            }
        }
}

// ---- gemm2 (MFMA, register-pipelined): [mu|lv] = ha @ [Wmu;Wlv] + bias -----
// In-place over ha panel: __syncthreads() between K-loop and epilogue.
__global__ __launch_bounds__(256, 2) void k_gemm2p(
    const unsigned short* __restrict__ hap,
    const unsigned short* __restrict__ bth,
    const unsigned short* __restrict__ btl,
    const void* bmu, const void* blv, const unsigned* __restrict__ det,
    float* __restrict__ outMu, float* __restrict__ outLv, int N) {
    const int lane = threadIdx.x & 63;
    const int wid  = threadIdx.x >> 6;
    const int wr = wid >> 1, wc = wid & 1;
    const int l15 = lane & 15, lg = lane >> 4;
    const long long r0 = (long long)blockIdx.x * 64 + wr * 32;
    long long ar[2];
#pragma unroll
    for (int m = 0; m < 2; ++m) {
        long long r = r0 + m * 16 + l15;
        ar[m] = (r < N) ? r : (N - 1);
    }
    int bn[4];
#pragma unroll
    for (int n = 0; n < 4; ++n) bn[n] = wc * 64 + n * 16 + l15;

    const unsigned short* aP[2];
#pragma unroll
    for (int m = 0; m < 2; ++m) aP[m] = hap + ar[m] * 128 + lg * 8;
    const unsigned short* bHp[4];
    const unsigned short* bLp[4];
#pragma unroll
    for (int n = 0; n < 4; ++n) {
        bHp[n] = bth + (long long)bn[n] * 128 + lg * 8;
        bLp[n] = btl + (long long)bn[n] * 128 + lg * 8;
    }
    f32x4 acc[2][4] = {};
    s16x8 aS[4][2], bhS[2][4], blS[2][4];
#pragma unroll
    for (int s = 0; s < 2; ++s)
#pragma unroll
        for (int m = 0; m < 2; ++m) aS[s][m] = ld8u(aP[m] + s * 32);
#pragma unroll
    for (int n = 0; n < 4; ++n) {
        bhS[0][n] = ld8u(bHp[n]);
        blS[0][n] = ld8u(bLp[n]);
    }
#pragma unroll
    for (int st = 0; st < 4; ++st) {
        if (st < 3) {
            const int nb = (st + 1) & 1;
#pragma unroll
            for (int n = 0; n < 4; ++n) {
                bhS[nb][n] = ld8u(bHp[n] + (st + 1) * 32);
                blS[nb][n] = ld8u(bLp[n] + (st + 1) * 32);
            }
        }
        if (st < 2) {
#pragma unroll
            for (int m = 0; m < 2; ++m)
                aS[st + 2][m] = ld8u(aP[m] + (st + 2) * 32);
        }
        const int cb = st & 1;
#pragma unroll
        for (int m = 0; m < 2; ++m)
#pragma unroll
            for (int n = 0; n < 4; ++n) {
                acc[m][n] = mfma16(aS[st][m], bhS[cb][n], acc[m][n]);
                acc[m][n] = mfma16(aS[st][m], blS[cb][n], acc[m][n]);
            }
    }
    __syncthreads();   // all A-reads done before any in-place mu write
    const unsigned wf = det[1];
#pragma unroll
    for (int m = 0; m < 2; ++m)
#pragma unroll
        for (int n = 0; n < 4; ++n) {
            const int col = wc * 64 + n * 16 + l15;
            const float bias = (col < 64) ? ldf(bmu, col, wf)
                                          : ldf(blv, col - 64, wf);
#pragma unroll
            for (int r = 0; r < 4; ++r) {
                long long row = r0 + m * 16 + lg * 4 + r;
                if (row < N) {
                    float v = acc[m][n][r] + bias;
                    if (col < 64) outMu[row * 64 + col] = v;
                    else          outLv[row * 64 + (col - 64)] = v;
                }
            }
        }
}

// ---- gather over pre-scaled bf16[N,128] panel ------------------------------
// out[node] = op( dinv[node] * (sum_{s in nbrs} h'[s] + h'[node]) )
// 2 nodes/wave: 32 lanes x uint2 (4 cols/lane), 8-way unroll -> 16 rows in
// flight per wave. pos = exclusive start (not mutated).
__global__ __launch_bounds__(256) void k_gather(const uint2* __restrict__ hp2,
                                                const int* __restrict__ srt,
                                                const int* __restrict__ cnt,
                                                const int* __restrict__ pos,
                                                const float* __restrict__ dinv,
                                                const void* bias, const unsigned* det,
                                                int leaky, int prescaleOut,
                                                uint2* __restrict__ outp2, int N) {
    int node = blockIdx.x * 8 + (threadIdx.x >> 5);
    if (node >= N) return;
    int lane5 = threadIdx.x & 31;
    int beg = pos[node];
    int end = beg + cnt[node];
    float dd = dinv[node];
    uint2 hv = hp2[(long long)node * 32 + lane5];
    float a0 = bf2f((unsigned short)(hv.x & 0xffffu));
    float a1 = bf2f((unsigned short)(hv.x >> 16));
    float a2 = bf2f((unsigned short)(hv.y & 0xffffu));
    float a3 = bf2f((unsigned short)(hv.y >> 16));
    for (int q = beg; q < end; q += 8) {
        int s[8];
        uint2 v[8];
#pragma unroll
        for (int j = 0; j < 8; ++j) {
            int qq = q + j;
            s[j] = srt[(qq < end) ? qq : beg];   // loop entered => beg valid
        }
#pragma unroll
        for (int j = 0; j < 8; ++j)
            v[j] = hp2[(long long)s[j] * 32 + lane5];
#pragma unroll
        for (int j = 0; j < 8; ++j) {
            bool on = (q + j) < end;
            a0 += on ? bf2f((unsigned short)(v[j].x & 0xffffu)) : 0.f;
            a1 += on ? bf2f((unsigned short)(v[j].x >> 16)) : 0.f;
            a2 += on ? bf2f((unsigned short)(v[j].y & 0xffffu)) : 0.f;
            a3 += on ? bf2f((unsigned short)(v[j].y >> 16)) : 0.f;
        }
    }
    a0 *= dd; a1 *= dd; a2 *= dd; a3 *= dd;
    if (bias) {
        a0 += ldf(bias, 4 * lane5 + 0, det[1]);
        a1 += ldf(bias, 4 * lane5 + 1, det[1]);
        a2 += ldf(bias, 4 * lane5 + 2, det[1]);
        a3 += ldf(bias, 4 * lane5 + 3, det[1]);
    }
    if (leaky) {
        a0 = (a0 >= 0.f) ? a0 : 0.01f * a0;
        a1 = (a1 >= 0.f) ? a1 : 0.01f * a1;
        a2 = (a2 >= 0.f) ? a2 : 0.01f * a2;
        a3 = (a3 >= 0.f) ? a3 : 0.01f * a3;
    }
    if (prescaleOut) { a0 *= dd; a1 *= dd; a2 *= dd; a3 *= dd; }
    uint2 o;
    o.x = pack2(a0, a1);
    o.y = pack2(a2, a3);
    outp2[(long long)node * 32 + lane5] = o;
}

__global__ void k_sentinel(float* out, long long lvOff) {
    if (threadIdx.x == 0 && blockIdx.x == 0) {
        out[0] = 9.99e5f;
        out[lvOff] = 9.98e5f;
    }
}

extern "C" void kernel_launch(void* const* d_in, const int* in_sizes, int n_in,
                              void* d_out, int out_size, void* d_ws, size_t ws_size,
                              hipStream_t stream) {
    (void)out_size;
    const int N = 100000, E = 1600000;
    bool ok = (n_in == 8) && in_sizes[0] == 25600000 && in_sizes[1] == 3200000 &&
              in_sizes[2] == 32768 && in_sizes[3] == 128 &&
              in_sizes[4] == 8192 && in_sizes[5] == 64 &&
              in_sizes[6] == 8192 && in_sizes[7] == 64 &&
              ws_size >= (size_t)21 * 1024 * 1024;
    if (!ok) {
        k_sentinel<<<1, 64, 0, stream>>>((float*)d_out, (long long)N * 64);
        return;
    }
    const void* x   = d_in[0];
    const void* ei  = d_in[1];
    const void* W1  = d_in[2];
    const void* b1  = d_in[3];
    const void* Wmu = d_in[4];
    const void* bmu = d_in[5];
    const void* Wlv = d_in[6];
    const void* blv = d_in[7];

    char* w = (char*)d_ws;
    auto carve = [&](size_t bytes) {
        char* p = w;
        w += (bytes + 255) & ~(size_t)255;
        return p;
    };
    unsigned* flags = (unsigned*)carve(64);
    int*    cnt  = (int*)carve((size_t)N * 4);
    int*    pos  = (int*)carve((size_t)N * 4);
    float*  dinv = (float*)carve((size_t)N * 4);
    int*    bsum = (int*)carve(4096);
    int*    srt  = (int*)carve((size_t)E * 4);
    unsigned short* bt1h = (unsigned short*)carve(128 * 256 * 2);  // 64KB
    unsigned short* bt1l = (unsigned short*)carve(128 * 256 * 2);
    unsigned short* bt2h = (unsigned short*)carve(128 * 128 * 2);  // 32KB
    unsigned short* bt2l = (unsigned short*)carve(128 * 128 * 2);
    int*      btail  = (int*)carve((size_t)NBKT * 8 * 4);               // 25KB
    unsigned* bstore = (unsigned*)carve((size_t)NBKT * 8 * CAPS * 4);   // 12.8MB
    // total ~20.6MB

    float* M = (float*)d_out;                  // mu region / panel storage
    float* L = M + (size_t)N * 64;             // logvar region / panel storage
    unsigned* Mp = (unsigned*)M;               // bf16[N,128] as dword[N*64]
    unsigned* Lp = (unsigned*)L;

    const int nb = (N + 1023) / 1024;
    const int ggrid = N / 8;                   // 12500 (N % 8 == 0)
    const int gb64 = (N + 63) / 64;            // 1563

    k_detect<<<1, 256, 0, stream>>>(x, W1, ei, flags, btail);
    k_wsplit<<<(256 * 128 + 128 * 128 + 255) / 256, 256, 0, stream>>>(
        W1, Wmu, Wlv, flags, bt1h, bt1l, bt2h, bt2l);

    // bucketed counting sort
    k_bucket<<<(E + 255) / 256, 256, 0, stream>>>(ei, flags, btail, bstore, E, N);
    k_bhist<<<NBKT, 256, 0, stream>>>(btail, bstore, cnt, dinv, N);
    k_scan_blk<<<nb, 256, 0, stream>>>(cnt, pos, bsum, N);
    k_scan_add<<<nb, 256, 0, stream>>>(pos, bsum, N);
    k_emit<<<NBKT, 256, 0, stream>>>(btail, bstore, pos, srt, N);

    // h0' = (x@W1) * dinv[row]  -> bf16 panel in M   (MFMA, reg-pipelined)
    k_gemm1p<<<gb64, 256, 0, stream>>>(x, flags, bt1h, bt1l, dinv, Mp, N);
    // h'  = leaky(dd*(sum+self) + b1) * dd -> bf16 panel in L
    k_gather<<<ggrid, 256, 0, stream>>>((const uint2*)Mp, srt, cnt, pos, dinv,
                                        b1, flags, 1, 1, (uint2*)Lp, N);
    // ha  = dd*(sum+self) -> bf16 panel in M (h0' dead)
    k_gather<<<ggrid, 256, 0, stream>>>((const uint2*)Lp, srt, cnt, pos, dinv,
                                        nullptr, flags, 0, 0, (uint2*)Mp, N);
    // [mu|lv] = ha @ [Wmu;Wlv] + bias -> fp32 M/L in-place  (MFMA, pipelined)
    k_gemm2p<<<gb64, 256, 0, stream>>>((const unsigned short*)Mp, bt2h, bt2l,
                                       bmu, blv, flags, M, L, N);
}